// Round 2
// baseline (1325.713 us; speedup 1.0000x reference)
//
#include <hip/hip_runtime.h>
#include <hip/hip_bf16.h>

#define NN 50000
#define EE 1600000
#define FIN 128
#define HH 32
#define CC 16
#define NB 782   // ceil(NN/64) coarse dst-buckets of 64 nodes

typedef unsigned short u16;
typedef unsigned int u32;
typedef unsigned char u8;

__device__ __forceinline__ float bf2f(u16 u) {
    union { u32 i; float f; } v; v.i = ((u32)u) << 16; return v.f;
}
__device__ __forceinline__ u16 f2bf(float f) {
    union { float f; u32 i; } v; v.f = f;
    u32 x = v.i;
    return (u16)((x + 0x7fffu + ((x >> 16) & 1u)) >> 16);  // RNE
}

// ---- dtype probe: flag=1 if float tensors are bf16, 0 if fp32 ----
__global__ __launch_bounds__(256) void k_probe(const u32* __restrict__ xw_words, int* __restrict__ flag) {
    __shared__ int cs;
    if (threadIdx.x == 0) cs = 0;
    __syncthreads();
    int c = 0;
    for (int i = threadIdx.x; i < 512; i += 256) {
        float v = fabsf(bf2f((u16)(xw_words[i] & 0xffffu)));
        if (v >= 6.0e-8f && v <= 64.0f) c++;
    }
    atomicAdd(&cs, c);
    __syncthreads();
    if (threadIdx.x == 0) *flag = (cs > 384) ? 1 : 0;
}

__global__ __launch_bounds__(256) void k_zero(int* __restrict__ p, int n) {
    int i = blockIdx.x * 256 + threadIdx.x;
    if (i < n) p[i] = 0;
}

__global__ __launch_bounds__(256) void k_deg(const int* __restrict__ dst, int* __restrict__ cnt) {
    int e = blockIdx.x * 256 + threadIdx.x;
    if (e < EE) atomicAdd(&cnt[dst[e]], 1);
}

// in-place: int counts -> float rsqrt(cnt+1)  (dis overlays cnt)
__global__ __launch_bounds__(256) void k_dis(int* __restrict__ p) {
    int i = blockIdx.x * 256 + threadIdx.x;
    if (i < NN) {
        float v = rsqrtf((float)p[i] + 1.0f);  // +1 = self-loop
        ((float*)p)[i] = v;
    }
}

// ---- exclusive prefix sum of cnt -> rowptr[0..NN], single block ----
__global__ __launch_bounds__(1024) void k_scan(const int* __restrict__ cnt, int* __restrict__ rowptr) {
    __shared__ int ps[1024];
    const int t = threadIdx.x;
    const int CH = (NN + 1023) / 1024;  // 49
    int b = t * CH;
    int e = b + CH; if (e > NN) e = NN;
    int s = 0;
    for (int i = b; i < e; ++i) s += cnt[i];
    ps[t] = s;
    __syncthreads();
    for (int off = 1; off < 1024; off <<= 1) {
        int v = (t >= off) ? ps[t - off] : 0;
        __syncthreads();
        ps[t] += v;
        __syncthreads();
    }
    int run = (t == 0) ? 0 : ps[t - 1];
    for (int i = b; i < e; ++i) { rowptr[i] = run; run += cnt[i]; }
    if (t == 1023) rowptr[NN] = ps[1023];
}

// bfill[cb] = rowptr[cb*64] (start of coarse bucket cb's segment)
__global__ __launch_bounds__(256) void k_bfill(const int* __restrict__ rowptr, int* __restrict__ bfill) {
    int i = blockIdx.x * 256 + threadIdx.x;
    if (i < NB) bfill[i] = rowptr[i * 64];
}

// ---- coarse-bin edges by dst>>6; store src (u16) + dst&63 (u8) ----
__global__ __launch_bounds__(256) void k_bin(const int* __restrict__ src, const int* __restrict__ dst,
                                             int* __restrict__ bfill, u16* __restrict__ src16,
                                             u8* __restrict__ rel8) {
    int e = blockIdx.x * 256 + threadIdx.x;
    if (e < EE) {
        int d = dst[e];
        int pos = atomicAdd(&bfill[d >> 6], 1);
        src16[pos] = (u16)src[e];
        rel8[pos] = (u8)(d & 63);
    }
}

// ---- xw = x @ W1 -> bf16 [NN,32]; x is [NN,128] bf16 or fp32 per flag ----
__global__ __launch_bounds__(256) void k_xw1(const void* __restrict__ xv, const void* __restrict__ W1v,
                                             const int* __restrict__ flag, u16* __restrict__ xwb) {
    __shared__ float wsm[FIN * HH];   // 16 KB
    __shared__ float xs[128][33];     // 16.9 KB
    const int f = *flag;
    const int tid = threadIdx.x;
    if (f) {
        const u16* W1 = (const u16*)W1v;
        for (int i = tid; i < FIN * HH; i += 256) wsm[i] = bf2f(W1[i]);
    } else {
        const float* W1 = (const float*)W1v;
        for (int i = tid; i < FIN * HH; i += 256) wsm[i] = W1[i];
    }
    const int n0 = blockIdx.x * 128;
    const int ct = tid & 7, rg = tid >> 3;
    const int lr = tid >> 1, lh = tid & 1;
    int ln = n0 + lr; if (ln >= NN) ln = NN - 1;
    float acc[4][4] = {};
    for (int kc = 0; kc < FIN; kc += 32) {
        __syncthreads();
        float* dq = &xs[lr][lh * 16];
        if (f) {
            const u16* lp = (const u16*)xv + (size_t)ln * FIN + lh * 16 + kc;
            uint4 a = *(const uint4*)lp;
            uint4 b = *(const uint4*)(lp + 8);
            u32 aw[4] = {a.x, a.y, a.z, a.w}, bw[4] = {b.x, b.y, b.z, b.w};
            #pragma unroll
            for (int i = 0; i < 4; ++i) {
                dq[2*i]     = bf2f((u16)(aw[i] & 0xffffu));
                dq[2*i+1]   = bf2f((u16)(aw[i] >> 16));
                dq[8+2*i]   = bf2f((u16)(bw[i] & 0xffffu));
                dq[8+2*i+1] = bf2f((u16)(bw[i] >> 16));
            }
        } else {
            const float* lp = (const float*)xv + (size_t)ln * FIN + lh * 16 + kc;
            #pragma unroll
            for (int i = 0; i < 4; ++i) {
                float4 t = *(const float4*)(lp + 4 * i);
                dq[4*i] = t.x; dq[4*i+1] = t.y; dq[4*i+2] = t.z; dq[4*i+3] = t.w;
            }
        }
        __syncthreads();
        #pragma unroll
        for (int k = 0; k < 32; ++k) {
            float4 wv = *(const float4*)&wsm[(kc + k) * HH + ct * 4];
            #pragma unroll
            for (int j = 0; j < 4; ++j) {
                float xvv = xs[rg * 4 + j][k];
                acc[j][0] = fmaf(xvv, wv.x, acc[j][0]);
                acc[j][1] = fmaf(xvv, wv.y, acc[j][1]);
                acc[j][2] = fmaf(xvv, wv.z, acc[j][2]);
                acc[j][3] = fmaf(xvv, wv.w, acc[j][3]);
            }
        }
    }
    #pragma unroll
    for (int j = 0; j < 4; ++j) {
        int n = n0 + rg * 4 + j;
        if (n < NN) {
            ushort4 o;
            o.x = f2bf(acc[j][0]); o.y = f2bf(acc[j][1]);
            o.z = f2bf(acc[j][2]); o.w = f2bf(acc[j][3]);
            *(ushort4*)&xwb[(size_t)n * HH + ct * 4] = o;
        }
    }
}

// ---- xw = h1 @ W2 -> bf16; h1 is bf16 [NN,32] (internal) ----
__global__ __launch_bounds__(256) void k_xw2(const u16* __restrict__ h1, const void* __restrict__ W2v,
                                             const int* __restrict__ flag, u16* __restrict__ xwb) {
    __shared__ float wsm[HH * HH];
    __shared__ float xs[128][33];
    const int f = *flag;
    const int tid = threadIdx.x;
    if (f) {
        const u16* W2 = (const u16*)W2v;
        for (int i = tid; i < HH * HH; i += 256) wsm[i] = bf2f(W2[i]);
    } else {
        const float* W2 = (const float*)W2v;
        for (int i = tid; i < HH * HH; i += 256) wsm[i] = W2[i];
    }
    const int n0 = blockIdx.x * 128;
    const int lr = tid >> 1, lh = tid & 1;
    int ln = n0 + lr; if (ln >= NN) ln = NN - 1;
    const u16* lp = h1 + (size_t)ln * HH + lh * 16;
    uint4 a = *(const uint4*)lp;
    uint4 b = *(const uint4*)(lp + 8);
    float* dq = &xs[lr][lh * 16];
    u32 aw[4] = {a.x, a.y, a.z, a.w}, bw[4] = {b.x, b.y, b.z, b.w};
    #pragma unroll
    for (int i = 0; i < 4; ++i) {
        dq[2*i]     = bf2f((u16)(aw[i] & 0xffffu));
        dq[2*i+1]   = bf2f((u16)(aw[i] >> 16));
        dq[8+2*i]   = bf2f((u16)(bw[i] & 0xffffu));
        dq[8+2*i+1] = bf2f((u16)(bw[i] >> 16));
    }
    __syncthreads();
    const int ct = tid & 7, rg = tid >> 3;
    float acc[4][4] = {};
    #pragma unroll
    for (int k = 0; k < 32; ++k) {
        float4 wv = *(const float4*)&wsm[k * HH + ct * 4];
        #pragma unroll
        for (int j = 0; j < 4; ++j) {
            float xv = xs[rg * 4 + j][k];
            acc[j][0] = fmaf(xv, wv.x, acc[j][0]);
            acc[j][1] = fmaf(xv, wv.y, acc[j][1]);
            acc[j][2] = fmaf(xv, wv.z, acc[j][2]);
            acc[j][3] = fmaf(xv, wv.w, acc[j][3]);
        }
    }
    #pragma unroll
    for (int j = 0; j < 4; ++j) {
        int n = n0 + rg * 4 + j;
        if (n < NN) {
            ushort4 o;
            o.x = f2bf(acc[j][0]); o.y = f2bf(acc[j][1]);
            o.z = f2bf(acc[j][2]); o.w = f2bf(acc[j][3]);
            *(ushort4*)&xwb[(size_t)n * HH + ct * 4] = o;
        }
    }
}

// ---- per-bucket LDS aggregation + fused epilogue ----
// block cb: agg[rel][ch] += dis[s]*xw[s][ch] over bucket edges, then
// out[n] = tanh( dis[n]*(agg + dis[n]*xw[n]) + bias )
__global__ __launch_bounds__(256) void k_agg(const int* __restrict__ rowptr, const u16* __restrict__ src16,
                                             const u8* __restrict__ rel8,
                                             const u16* __restrict__ xwb, const float* __restrict__ dis,
                                             const void* __restrict__ bv, const int* __restrict__ flag,
                                             int force16, u16* __restrict__ dst16, float* __restrict__ dst32) {
    __shared__ float agg[64 * HH];  // 8 KB
    const int f = *flag;
    const int tid = threadIdx.x;
    const int cb = blockIdx.x;
    const int node0 = cb * 64;
    int nend = node0 + 64; if (nend > NN) nend = NN;
    const int beg = rowptr[node0];
    const int end = rowptr[nend];
    for (int t = tid; t < 64 * HH; t += 256) agg[t] = 0.f;
    __syncthreads();
    const int g = tid >> 5, lane = tid & 31;
    int i = beg + g;
    for (; i + 8 < end; i += 16) {
        int sA = src16[i];     int sB = src16[i + 8];
        int rA = rel8[i];      int rB = rel8[i + 8];
        float wA = dis[sA], wB = dis[sB];
        float vA = wA * bf2f(xwb[(size_t)sA * HH + lane]);
        float vB = wB * bf2f(xwb[(size_t)sB * HH + lane]);
        atomicAdd(&agg[rA * HH + lane], vA);
        atomicAdd(&agg[rB * HH + lane], vB);
    }
    if (i < end) {
        int s = src16[i]; int r = rel8[i];
        atomicAdd(&agg[r * HH + lane], dis[s] * bf2f(xwb[(size_t)s * HH + lane]));
    }
    __syncthreads();
    for (int t = tid; t < 64 * HH; t += 256) {
        int n = node0 + (t >> 5);
        if (n < NN) {
            int c = t & 31;
            float bias = f ? bf2f(((const u16*)bv)[c]) : ((const float*)bv)[c];
            float dd = dis[n];
            float self = bf2f(xwb[(size_t)n * HH + c]);
            float v = tanhf(fmaf(dd, fmaf(dd, self, agg[t]), bias));
            size_t idx = (size_t)n * HH + c;
            if (force16 | f) dst16[idx] = f2bf(v);
            else             dst32[idx] = v;
        }
    }
}

// ---- classifier: logits = h2 @ Wc + bc ----
__global__ __launch_bounds__(256) void k_cls(void* __restrict__ outbase, const void* __restrict__ Wcv,
                                             const void* __restrict__ bcv, const int* __restrict__ flag) {
    __shared__ float wsm[HH * CC];
    __shared__ float bs[CC];
    const int f = *flag;
    int tid = threadIdx.x;
    if (f) {
        const u16* Wc = (const u16*)Wcv;
        for (int i = tid; i < HH * CC; i += 256) wsm[i] = bf2f(Wc[i]);
        if (tid < CC) bs[tid] = bf2f(((const u16*)bcv)[tid]);
    } else {
        const float* Wc = (const float*)Wcv;
        for (int i = tid; i < HH * CC; i += 256) wsm[i] = Wc[i];
        if (tid < CC) bs[tid] = ((const float*)bcv)[tid];
    }
    __syncthreads();
    int t = blockIdx.x * 256 + tid;
    int n = t >> 4;
    if (n < NN) {
        int cl = t & 15;
        float acc = bs[cl];
        if (f) {
            const u16* r = (const u16*)outbase + (size_t)NN * CC + (size_t)n * HH;
            #pragma unroll
            for (int k = 0; k < HH; ++k) acc = fmaf(bf2f(r[k]), wsm[k * CC + cl], acc);
            ((u16*)outbase)[t] = f2bf(acc);
        } else {
            const float* r = (const float*)outbase + (size_t)NN * CC + (size_t)n * HH;
            #pragma unroll
            for (int k = 0; k < HH; ++k) acc = fmaf(r[k], wsm[k * CC + cl], acc);
            ((float*)outbase)[t] = acc;
        }
    }
}

extern "C" void kernel_launch(void* const* d_in, const int* in_sizes, int n_in,
                              void* d_out, int out_size, void* d_ws, size_t ws_size,
                              hipStream_t stream) {
    const void* x  = d_in[0];
    const int*  ei = (const int*)d_in[1];
    const void* W1 = d_in[2];
    const void* b1 = d_in[3];
    const void* W2 = d_in[4];
    const void* b2 = d_in[5];
    const void* Wc = d_in[6];
    const void* bc = d_in[7];
    const int* srcv = ei;
    const int* dstv = ei + EE;

    // ws layout (bytes), total 8.42 MB (ws >= 9.8 MB proven in prior session):
    //   [0, 4096)              flag
    //   [4096, 208896)         rowptr int[N+1]
    //   [208896, 413696)       cnt int[N] -> dis f32[N] (in-place overlay)
    //   [413696, 417792)       bfill int[NB]
    //   [417792, 3620864)      xwb  bf16[N*32]
    //   [3620864, 6823936)     src16 u16[E]
    //   [6823936, 8423936)     rel8  u8[E]
    char*  ws     = (char*)d_ws;
    int*   flag   = (int*)ws;
    int*   rowptr = (int*)(ws + 4096);
    int*   cnt    = (int*)(ws + 208896);
    float* dis    = (float*)(ws + 208896);
    int*   bfill  = (int*)(ws + 413696);
    u16*   xwb    = (u16*)(ws + 417792);
    u16*   src16  = (u16*)(ws + 3620864);
    u8*    rel8   = (u8*)(ws + 6823936);

    // h1 (bf16, internal) lives in d_out's head; h2 goes to its final slot.
    u16*   h1    = (u16*)d_out;
    u16*   h2_16 = (u16*)d_out + (size_t)NN * CC;
    float* h2_32 = (float*)d_out + (size_t)NN * CC;

    k_probe<<<1, 256, 0, stream>>>((const u32*)x, flag);
    k_zero<<<(NN + 255) / 256, 256, 0, stream>>>(cnt, NN);
    k_deg<<<(EE + 255) / 256, 256, 0, stream>>>(dstv, cnt);
    k_scan<<<1, 1024, 0, stream>>>(cnt, rowptr);   // reads cnt (int)
    k_dis<<<(NN + 255) / 256, 256, 0, stream>>>(cnt);  // cnt -> dis in place
    k_bfill<<<(NB + 255) / 256, 256, 0, stream>>>(rowptr, bfill);
    k_bin<<<(EE + 255) / 256, 256, 0, stream>>>(srcv, dstv, bfill, src16, rel8);

    // layer 1: xw1 -> per-bucket LDS agg (fused norm+bias+tanh) -> h1 (bf16)
    k_xw1<<<(NN + 127) / 128, 256, 0, stream>>>(x, W1, flag, xwb);
    k_agg<<<NB, 256, 0, stream>>>(rowptr, src16, rel8, xwb, dis, b1, flag,
                                  1, h1, (float*)nullptr);

    // layer 2: xw2 (reads h1) -> agg -> h2 (final slot, dtype per flag)
    k_xw2<<<(NN + 127) / 128, 256, 0, stream>>>(h1, W2, flag, xwb);
    k_agg<<<NB, 256, 0, stream>>>(rowptr, src16, rel8, xwb, dis, b2, flag,
                                  0, h2_16, h2_32);

    // classifier
    k_cls<<<(NN * CC + 255) / 256, 256, 0, stream>>>(d_out, Wc, bc, flag);
}

// Round 3
// 328.972 us; speedup vs baseline: 4.0299x; 4.0299x over previous
//
#include <hip/hip_runtime.h>
#include <hip/hip_bf16.h>

#define NN 50000
#define EE 1600000
#define FIN 128
#define HH 32
#define CC 16
#define NB 782        // ceil(NN/64) coarse dst-buckets of 64 nodes
#define NBLK 196      // edge-chunk blocks: 196 * 8192 >= EE
#define CHUNK 8192

typedef unsigned short u16;
typedef unsigned int u32;
typedef unsigned char u8;

__device__ __forceinline__ float bf2f(u16 u) {
    union { u32 i; float f; } v; v.i = ((u32)u) << 16; return v.f;
}
__device__ __forceinline__ u16 f2bf(float f) {
    union { float f; u32 i; } v; v.f = f;
    u32 x = v.i;
    return (u16)((x + 0x7fffu + ((x >> 16) & 1u)) >> 16);  // RNE
}

// ---- dtype probe: flag=1 if float tensors are bf16, 0 if fp32 ----
__global__ __launch_bounds__(256) void k_probe(const u32* __restrict__ xw_words, int* __restrict__ flag) {
    __shared__ int cs;
    if (threadIdx.x == 0) cs = 0;
    __syncthreads();
    int c = 0;
    for (int i = threadIdx.x; i < 512; i += 256) {
        float v = fabsf(bf2f((u16)(xw_words[i] & 0xffffu)));
        if (v >= 6.0e-8f && v <= 64.0f) c++;
    }
    atomicAdd(&cs, c);
    __syncthreads();
    if (threadIdx.x == 0) *flag = (cs > 384) ? 1 : 0;
}

// ---- per-block coarse histogram of dst>>6 (no global atomics) ----
__global__ __launch_bounds__(256) void k_hist(const int* __restrict__ dst, int* __restrict__ hist_g) {
    __shared__ int h[NB];
    const int tid = threadIdx.x;
    for (int i = tid; i < NB; i += 256) h[i] = 0;
    __syncthreads();
    const int e0 = blockIdx.x * CHUNK;
    #pragma unroll 4
    for (int k = 0; k < CHUNK / 256; ++k) {
        int e = e0 + k * 256 + tid;
        if (e < EE) atomicAdd(&h[dst[e] >> 6], 1);
    }
    __syncthreads();
    for (int i = tid; i < NB; i += 256) hist_g[blockIdx.x * NB + i] = h[i];
}

// ---- bases: cbase[cb] = prefix over buckets; hist_g[b][cb] -> per-block base ----
__global__ __launch_bounds__(1024) void k_bscan(int* __restrict__ hist_g, int* __restrict__ cbase) {
    __shared__ int ps[1024];
    const int t = threadIdx.x;
    int total = 0;
    if (t < NB) {
        for (int b = 0; b < NBLK; ++b) total += hist_g[b * NB + t];
    }
    ps[t] = (t < NB) ? total : 0;
    __syncthreads();
    for (int off = 1; off < 1024; off <<= 1) {
        int v = (t >= off) ? ps[t - off] : 0;
        __syncthreads();
        ps[t] += v;
        __syncthreads();
    }
    int base = (t == 0) ? 0 : ps[t - 1];  // exclusive
    if (t < NB) {
        cbase[t] = base;
        int run = base;
        for (int b = 0; b < NBLK; ++b) {
            int hv = hist_g[b * NB + t];
            hist_g[b * NB + t] = run;  // becomes this block's write base for bucket t
            run += hv;
        }
    }
    if (t == 0) cbase[NB] = EE;
}

// ---- place edges coarse-grouped (src u16 + rel u8), no global atomics ----
__global__ __launch_bounds__(256) void k_place(const int* __restrict__ src, const int* __restrict__ dst,
                                               const int* __restrict__ hist_g,
                                               u16* __restrict__ csrc16, u8* __restrict__ crel8) {
    __shared__ int cur[NB];
    const int tid = threadIdx.x;
    const int blk = blockIdx.x;
    for (int i = tid; i < NB; i += 256) cur[i] = hist_g[blk * NB + i];
    __syncthreads();
    const int e0 = blk * CHUNK;
    #pragma unroll 4
    for (int k = 0; k < CHUNK / 256; ++k) {
        int e = e0 + k * 256 + tid;
        if (e < EE) {
            int d = dst[e];
            int pos = atomicAdd(&cur[d >> 6], 1);  // LDS atomic only
            csrc16[pos] = (u16)src[e];
            crel8[pos] = (u8)(d & 63);
        }
    }
}

// ---- fine counts per node from coarse segments ----
__global__ __launch_bounds__(256) void k_fcnt(const int* __restrict__ cbase, const u8* __restrict__ crel8,
                                              int* __restrict__ cnt) {
    __shared__ int h[64];
    const int tid = threadIdx.x;
    const int cb = blockIdx.x;
    if (tid < 64) h[tid] = 0;
    __syncthreads();
    const int b0 = cbase[cb], b1 = cbase[cb + 1];
    for (int i = b0 + tid; i < b1; i += 256) atomicAdd(&h[crel8[i]], 1);
    __syncthreads();
    if (tid < 64) {
        int n = cb * 64 + tid;
        if (n < NN) cnt[n] = h[tid];
    }
}

// ---- exclusive prefix sum of cnt -> rowptr[0..NN], single block ----
__global__ __launch_bounds__(1024) void k_scan(const int* __restrict__ cnt, int* __restrict__ rowptr) {
    __shared__ int ps[1024];
    const int t = threadIdx.x;
    const int CH = (NN + 1023) / 1024;  // 49
    int b = t * CH;
    int e = b + CH; if (e > NN) e = NN;
    int s = 0;
    for (int i = b; i < e; ++i) s += cnt[i];
    ps[t] = s;
    __syncthreads();
    for (int off = 1; off < 1024; off <<= 1) {
        int v = (t >= off) ? ps[t - off] : 0;
        __syncthreads();
        ps[t] += v;
        __syncthreads();
    }
    int run = (t == 0) ? 0 : ps[t - 1];
    for (int i = b; i < e; ++i) { rowptr[i] = run; run += cnt[i]; }
    if (t == 1023) rowptr[NN] = ps[1023];
}

// in-place: int counts -> float rsqrt(cnt+1)  (dis overlays cnt)
__global__ __launch_bounds__(256) void k_dis(int* __restrict__ p) {
    int i = blockIdx.x * 256 + threadIdx.x;
    if (i < NN) {
        float v = rsqrtf((float)p[i] + 1.0f);  // +1 = self-loop
        ((float*)p)[i] = v;
    }
}

// ---- regroup coarse segment by exact dst node -> fine CSR entries ----
__global__ __launch_bounds__(256) void k_fine(const int* __restrict__ cbase, const int* __restrict__ rowptr,
                                              const u16* __restrict__ csrc16, const u8* __restrict__ crel8,
                                              u16* __restrict__ entries) {
    __shared__ int cur[64];
    const int tid = threadIdx.x;
    const int cb = blockIdx.x;
    const int node0 = cb * 64;
    if (tid < 64) {
        int n = node0 + tid;
        cur[tid] = (n < NN) ? rowptr[n] : 0;
    }
    __syncthreads();
    const int b0 = cbase[cb], b1 = cbase[cb + 1];
    for (int i = b0 + tid; i < b1; i += 256) {
        int r = crel8[i];
        int pos = atomicAdd(&cur[r], 1);  // LDS atomic only
        entries[pos] = csrc16[i];
    }
}

// ---- xws = dis[n] * (x @ W1) -> bf16 [NN,32]; x is [NN,128] bf16 or fp32 ----
__global__ __launch_bounds__(256) void k_xw1(const void* __restrict__ xv, const void* __restrict__ W1v,
                                             const float* __restrict__ dis,
                                             const int* __restrict__ flag, u16* __restrict__ xwb) {
    __shared__ float wsm[FIN * HH];   // 16 KB
    __shared__ float xs[128][33];     // 16.9 KB
    const int f = *flag;
    const int tid = threadIdx.x;
    if (f) {
        const u16* W1 = (const u16*)W1v;
        for (int i = tid; i < FIN * HH; i += 256) wsm[i] = bf2f(W1[i]);
    } else {
        const float* W1 = (const float*)W1v;
        for (int i = tid; i < FIN * HH; i += 256) wsm[i] = W1[i];
    }
    const int n0 = blockIdx.x * 128;
    const int ct = tid & 7, rg = tid >> 3;
    const int lr = tid >> 1, lh = tid & 1;
    int ln = n0 + lr; if (ln >= NN) ln = NN - 1;
    float acc[4][4] = {};
    for (int kc = 0; kc < FIN; kc += 32) {
        __syncthreads();
        float* dq = &xs[lr][lh * 16];
        if (f) {
            const u16* lp = (const u16*)xv + (size_t)ln * FIN + lh * 16 + kc;
            uint4 a = *(const uint4*)lp;
            uint4 b = *(const uint4*)(lp + 8);
            u32 aw[4] = {a.x, a.y, a.z, a.w}, bw[4] = {b.x, b.y, b.z, b.w};
            #pragma unroll
            for (int i = 0; i < 4; ++i) {
                dq[2*i]     = bf2f((u16)(aw[i] & 0xffffu));
                dq[2*i+1]   = bf2f((u16)(aw[i] >> 16));
                dq[8+2*i]   = bf2f((u16)(bw[i] & 0xffffu));
                dq[8+2*i+1] = bf2f((u16)(bw[i] >> 16));
            }
        } else {
            const float* lp = (const float*)xv + (size_t)ln * FIN + lh * 16 + kc;
            #pragma unroll
            for (int i = 0; i < 4; ++i) {
                float4 t = *(const float4*)(lp + 4 * i);
                dq[4*i] = t.x; dq[4*i+1] = t.y; dq[4*i+2] = t.z; dq[4*i+3] = t.w;
            }
        }
        __syncthreads();
        #pragma unroll
        for (int k = 0; k < 32; ++k) {
            float4 wv = *(const float4*)&wsm[(kc + k) * HH + ct * 4];
            #pragma unroll
            for (int j = 0; j < 4; ++j) {
                float xvv = xs[rg * 4 + j][k];
                acc[j][0] = fmaf(xvv, wv.x, acc[j][0]);
                acc[j][1] = fmaf(xvv, wv.y, acc[j][1]);
                acc[j][2] = fmaf(xvv, wv.z, acc[j][2]);
                acc[j][3] = fmaf(xvv, wv.w, acc[j][3]);
            }
        }
    }
    #pragma unroll
    for (int j = 0; j < 4; ++j) {
        int n = n0 + rg * 4 + j;
        if (n < NN) {
            float dd = dis[n];
            ushort4 o;
            o.x = f2bf(dd * acc[j][0]); o.y = f2bf(dd * acc[j][1]);
            o.z = f2bf(dd * acc[j][2]); o.w = f2bf(dd * acc[j][3]);
            *(ushort4*)&xwb[(size_t)n * HH + ct * 4] = o;
        }
    }
}

// ---- xws = dis[n] * (h1 @ W2) -> bf16; h1 is bf16 [NN,32] (internal) ----
__global__ __launch_bounds__(256) void k_xw2(const u16* __restrict__ h1, const void* __restrict__ W2v,
                                             const float* __restrict__ dis,
                                             const int* __restrict__ flag, u16* __restrict__ xwb) {
    __shared__ float wsm[HH * HH];
    __shared__ float xs[128][33];
    const int f = *flag;
    const int tid = threadIdx.x;
    if (f) {
        const u16* W2 = (const u16*)W2v;
        for (int i = tid; i < HH * HH; i += 256) wsm[i] = bf2f(W2[i]);
    } else {
        const float* W2 = (const float*)W2v;
        for (int i = tid; i < HH * HH; i += 256) wsm[i] = W2[i];
    }
    const int n0 = blockIdx.x * 128;
    const int lr = tid >> 1, lh = tid & 1;
    int ln = n0 + lr; if (ln >= NN) ln = NN - 1;
    const u16* lp = h1 + (size_t)ln * HH + lh * 16;
    uint4 a = *(const uint4*)lp;
    uint4 b = *(const uint4*)(lp + 8);
    float* dq = &xs[lr][lh * 16];
    u32 aw[4] = {a.x, a.y, a.z, a.w}, bw[4] = {b.x, b.y, b.z, b.w};
    #pragma unroll
    for (int i = 0; i < 4; ++i) {
        dq[2*i]     = bf2f((u16)(aw[i] & 0xffffu));
        dq[2*i+1]   = bf2f((u16)(aw[i] >> 16));
        dq[8+2*i]   = bf2f((u16)(bw[i] & 0xffffu));
        dq[8+2*i+1] = bf2f((u16)(bw[i] >> 16));
    }
    __syncthreads();
    const int ct = tid & 7, rg = tid >> 3;
    float acc[4][4] = {};
    #pragma unroll
    for (int k = 0; k < 32; ++k) {
        float4 wv = *(const float4*)&wsm[k * HH + ct * 4];
        #pragma unroll
        for (int j = 0; j < 4; ++j) {
            float xv = xs[rg * 4 + j][k];
            acc[j][0] = fmaf(xv, wv.x, acc[j][0]);
            acc[j][1] = fmaf(xv, wv.y, acc[j][1]);
            acc[j][2] = fmaf(xv, wv.z, acc[j][2]);
            acc[j][3] = fmaf(xv, wv.w, acc[j][3]);
        }
    }
    #pragma unroll
    for (int j = 0; j < 4; ++j) {
        int n = n0 + rg * 4 + j;
        if (n < NN) {
            float dd = dis[n];
            ushort4 o;
            o.x = f2bf(dd * acc[j][0]); o.y = f2bf(dd * acc[j][1]);
            o.z = f2bf(dd * acc[j][2]); o.w = f2bf(dd * acc[j][3]);
            *(ushort4*)&xwb[(size_t)n * HH + ct * 4] = o;
        }
    }
}

// ---- CSR gather + fused epilogue: one node per 32-lane group ----
// xws rows are pre-scaled by dis[src]; self term is the scaled row itself.
// out[n] = tanh( dis[n] * ( xws[n] + sum_{s in N(n)} xws[s] ) + bias )
__global__ __launch_bounds__(256) void k_gather(const int* __restrict__ rowptr, const u16* __restrict__ entries,
                                                const u16* __restrict__ xws, const float* __restrict__ dis,
                                                const void* __restrict__ bv, const int* __restrict__ flag,
                                                int force16, u16* __restrict__ dst16, float* __restrict__ dst32) {
    const int f = *flag;
    int g = (blockIdx.x * 256 + threadIdx.x) >> 5;  // node
    int lane = threadIdx.x & 31;                    // channel
    if (g >= NN) return;
    float bias = f ? bf2f(((const u16*)bv)[lane]) : ((const float*)bv)[lane];
    const int beg = rowptr[g], end = rowptr[g + 1];
    const float dd = dis[g];
    float acc0 = bf2f(xws[(size_t)g * HH + lane]);  // self-loop (already scaled)
    float acc1 = 0.f, acc2 = 0.f, acc3 = 0.f;
    int i = beg;
    for (; i + 4 <= end; i += 4) {
        int s0 = entries[i], s1 = entries[i + 1], s2 = entries[i + 2], s3 = entries[i + 3];
        acc0 += bf2f(xws[(size_t)s0 * HH + lane]);
        acc1 += bf2f(xws[(size_t)s1 * HH + lane]);
        acc2 += bf2f(xws[(size_t)s2 * HH + lane]);
        acc3 += bf2f(xws[(size_t)s3 * HH + lane]);
    }
    for (; i < end; ++i) {
        acc0 += bf2f(xws[(size_t)entries[i] * HH + lane]);
    }
    float v = tanhf(fmaf(dd, (acc0 + acc1) + (acc2 + acc3), bias));
    size_t idx = (size_t)g * HH + lane;
    if (force16 | f) dst16[idx] = f2bf(v);
    else             dst32[idx] = v;
}

// ---- classifier: logits = h2 @ Wc + bc ----
__global__ __launch_bounds__(256) void k_cls(void* __restrict__ outbase, const void* __restrict__ Wcv,
                                             const void* __restrict__ bcv, const int* __restrict__ flag) {
    __shared__ float wsm[HH * CC];
    __shared__ float bs[CC];
    const int f = *flag;
    int tid = threadIdx.x;
    if (f) {
        const u16* Wc = (const u16*)Wcv;
        for (int i = tid; i < HH * CC; i += 256) wsm[i] = bf2f(Wc[i]);
        if (tid < CC) bs[tid] = bf2f(((const u16*)bcv)[tid]);
    } else {
        const float* Wc = (const float*)Wcv;
        for (int i = tid; i < HH * CC; i += 256) wsm[i] = Wc[i];
        if (tid < CC) bs[tid] = ((const float*)bcv)[tid];
    }
    __syncthreads();
    int t = blockIdx.x * 256 + tid;
    int n = t >> 4;
    if (n < NN) {
        int cl = t & 15;
        float acc = bs[cl];
        if (f) {
            const u16* r = (const u16*)outbase + (size_t)NN * CC + (size_t)n * HH;
            #pragma unroll
            for (int k = 0; k < HH; ++k) acc = fmaf(bf2f(r[k]), wsm[k * CC + cl], acc);
            ((u16*)outbase)[t] = f2bf(acc);
        } else {
            const float* r = (const float*)outbase + (size_t)NN * CC + (size_t)n * HH;
            #pragma unroll
            for (int k = 0; k < HH; ++k) acc = fmaf(r[k], wsm[k * CC + cl], acc);
            ((float*)outbase)[t] = acc;
        }
    }
}

extern "C" void kernel_launch(void* const* d_in, const int* in_sizes, int n_in,
                              void* d_out, int out_size, void* d_ws, size_t ws_size,
                              hipStream_t stream) {
    const void* x  = d_in[0];
    const int*  ei = (const int*)d_in[1];
    const void* W1 = d_in[2];
    const void* b1 = d_in[3];
    const void* W2 = d_in[4];
    const void* b2 = d_in[5];
    const void* Wc = d_in[6];
    const void* bc = d_in[7];
    const int* srcv = ei;
    const int* dstv = ei + EE;

    // ws layout (bytes), total ~7.43 MB:
    //   [0, 4096)              flag
    //   [4096, 208896)         rowptr int[N+1]
    //   [208896, 413696)       cnt int[N] -> dis f32[N] (in-place overlay)
    //   [413696, 417792)       cbase int[NB+1]
    //   [417792, 1032192)      hist_g int[NBLK*NB] (613 KB)
    //   [1032192, 4232192)     xwb  bf16[N*32]
    //   [4232192, 7432192)     entries u16[E]
    char*  ws     = (char*)d_ws;
    int*   flag   = (int*)ws;
    int*   rowptr = (int*)(ws + 4096);
    int*   cnt    = (int*)(ws + 208896);
    float* dis    = (float*)(ws + 208896);
    int*   cbase  = (int*)(ws + 413696);
    int*   hist_g = (int*)(ws + 417792);
    u16*   xwb    = (u16*)(ws + 1032192);
    u16*   entries= (u16*)(ws + 4232192);

    // Coarse-grouped temporaries live in d_out's head (consumed before h1 is
    // written there). csrc16: 3.2 MB, crel8: 1.6 MB -> 4.8 MB = min(out_size).
    u16*   csrc16 = (u16*)d_out;
    u8*    crel8  = (u8*)d_out + (size_t)EE * 2;

    // h1 (bf16, internal) lives in d_out's head; h2 goes to its final slot.
    u16*   h1    = (u16*)d_out;
    u16*   h2_16 = (u16*)d_out + (size_t)NN * CC;
    float* h2_32 = (float*)d_out + (size_t)NN * CC;

    k_probe<<<1, 256, 0, stream>>>((const u32*)x, flag);

    // deterministic two-level CSR build (zero global atomics)
    k_hist<<<NBLK, 256, 0, stream>>>(dstv, hist_g);
    k_bscan<<<1, 1024, 0, stream>>>(hist_g, cbase);
    k_place<<<NBLK, 256, 0, stream>>>(srcv, dstv, hist_g, csrc16, crel8);
    k_fcnt<<<NB, 256, 0, stream>>>(cbase, crel8, cnt);
    k_scan<<<1, 1024, 0, stream>>>(cnt, rowptr);
    k_dis<<<(NN + 255) / 256, 256, 0, stream>>>(cnt);  // cnt -> dis in place
    k_fine<<<NB, 256, 0, stream>>>(cbase, rowptr, csrc16, crel8, entries);

    // layer 1: xws1 (dis-scaled) -> gather (fused agg+bias+tanh) -> h1 (bf16)
    k_xw1<<<(NN + 127) / 128, 256, 0, stream>>>(x, W1, dis, flag, xwb);
    k_gather<<<((NN * 32) + 255) / 256, 256, 0, stream>>>(rowptr, entries, xwb, dis, b1, flag,
                                                          1, h1, (float*)nullptr);

    // layer 2: xws2 (reads h1) -> gather -> h2 (final slot, dtype per flag)
    k_xw2<<<(NN + 127) / 128, 256, 0, stream>>>(h1, W2, dis, flag, xwb);
    k_gather<<<((NN * 32) + 255) / 256, 256, 0, stream>>>(rowptr, entries, xwb, dis, b2, flag,
                                                          0, h2_16, h2_32);

    // classifier
    k_cls<<<(NN * CC + 255) / 256, 256, 0, stream>>>(d_out, Wc, bc, flag);
}

// Round 4
// 234.066 us; speedup vs baseline: 5.6639x; 1.4055x over previous
//
#include <hip/hip_runtime.h>
#include <hip/hip_bf16.h>

#define NN 50000
#define EE 1600000
#define FIN 128
#define HH 32
#define CC 16
#define NB 782        // ceil(NN/64) coarse dst-buckets of 64 nodes
#define NBLK 196      // edge-chunk blocks: 196 * 8192 >= EE
#define CHUNK 8192

typedef unsigned short u16;
typedef unsigned int u32;
typedef unsigned char u8;

__device__ __forceinline__ float bf2f(u16 u) {
    union { u32 i; float f; } v; v.i = ((u32)u) << 16; return v.f;
}
__device__ __forceinline__ u16 f2bf(float f) {
    union { float f; u32 i; } v; v.f = f;
    u32 x = v.i;
    return (u16)((x + 0x7fffu + ((x >> 16) & 1u)) >> 16);  // RNE
}

// ---- dtype probe: flag=1 if float tensors are bf16, 0 if fp32 ----
__global__ __launch_bounds__(256) void k_probe(const u32* __restrict__ xw_words, int* __restrict__ flag) {
    __shared__ int cs;
    if (threadIdx.x == 0) cs = 0;
    __syncthreads();
    int c = 0;
    for (int i = threadIdx.x; i < 512; i += 256) {
        float v = fabsf(bf2f((u16)(xw_words[i] & 0xffffu)));
        if (v >= 6.0e-8f && v <= 64.0f) c++;
    }
    atomicAdd(&cs, c);
    __syncthreads();
    if (threadIdx.x == 0) *flag = (cs > 384) ? 1 : 0;
}

// ---- per-block coarse histogram of dst>>6 (no global atomics) ----
__global__ __launch_bounds__(256) void k_hist(const int* __restrict__ dst, int* __restrict__ hist_g) {
    __shared__ int h[NB];
    const int tid = threadIdx.x;
    for (int i = tid; i < NB; i += 256) h[i] = 0;
    __syncthreads();
    const int e0 = blockIdx.x * CHUNK;
    #pragma unroll 4
    for (int k = 0; k < CHUNK / 256; ++k) {
        int e = e0 + k * 256 + tid;
        if (e < EE) atomicAdd(&h[dst[e] >> 6], 1);
    }
    __syncthreads();
    for (int i = tid; i < NB; i += 256) hist_g[blockIdx.x * NB + i] = h[i];
}

// ---- per-bucket scan over the 196 per-block histogram entries ----
// hist_g[b][cb] -> exclusive prefix within column cb; btot[cb] = column total
__global__ __launch_bounds__(256) void k_rscan(int* __restrict__ hist_g, int* __restrict__ btot) {
    __shared__ int ps[256];
    const int t = threadIdx.x;
    const int cb = blockIdx.x;
    int myv = (t < NBLK) ? hist_g[t * NB + cb] : 0;
    ps[t] = myv;
    __syncthreads();
    for (int off = 1; off < 256; off <<= 1) {
        int v = (t >= off) ? ps[t - off] : 0;
        __syncthreads();
        ps[t] += v;
        __syncthreads();
    }
    if (t < NBLK) hist_g[t * NB + cb] = ps[t] - myv;  // exclusive
    if (t == 255) btot[cb] = ps[255];
}

// ---- tiny single-block scan over bucket totals (3 KB only) ----
__global__ __launch_bounds__(1024) void k_cscan(const int* __restrict__ btot, int* __restrict__ cbase,
                                                int* __restrict__ rowptr) {
    __shared__ int ps[1024];
    const int t = threadIdx.x;
    int myv = (t < NB) ? btot[t] : 0;
    ps[t] = myv;
    __syncthreads();
    for (int off = 1; off < 1024; off <<= 1) {
        int v = (t >= off) ? ps[t - off] : 0;
        __syncthreads();
        ps[t] += v;
        __syncthreads();
    }
    if (t < NB) cbase[t] = ps[t] - myv;  // exclusive
    if (t == 0) { cbase[NB] = EE; rowptr[NN] = EE; }
}

// ---- place edges coarse-grouped (src u16 + rel u8), no global atomics ----
__global__ __launch_bounds__(256) void k_place(const int* __restrict__ src, const int* __restrict__ dst,
                                               const int* __restrict__ hist_g, const int* __restrict__ cbase,
                                               u16* __restrict__ csrc16, u8* __restrict__ crel8) {
    __shared__ int cur[NB];
    const int tid = threadIdx.x;
    const int blk = blockIdx.x;
    for (int i = tid; i < NB; i += 256) cur[i] = cbase[i] + hist_g[blk * NB + i];
    __syncthreads();
    const int e0 = blk * CHUNK;
    #pragma unroll 4
    for (int k = 0; k < CHUNK / 256; ++k) {
        int e = e0 + k * 256 + tid;
        if (e < EE) {
            int d = dst[e];
            int pos = atomicAdd(&cur[d >> 6], 1);  // LDS atomic only
            csrc16[pos] = (u16)src[e];
            crel8[pos] = (u8)(d & 63);
        }
    }
}

// ---- fused fine stage (per bucket): count 64 bins, local scan, write
//      rowptr + dis, regroup entries by exact node. All from L2-hot segment.
__global__ __launch_bounds__(256) void k_fine(const int* __restrict__ cbase, const int* __restrict__ rowptr_unused,
                                              const u16* __restrict__ csrc16, const u8* __restrict__ crel8,
                                              int* __restrict__ rowptr, float* __restrict__ dis,
                                              u16* __restrict__ entries) {
    __shared__ int h[64];
    __shared__ int ps[256];
    __shared__ int cur[64];
    const int tid = threadIdx.x;
    const int cb = blockIdx.x;
    const int node0 = cb * 64;
    if (tid < 64) h[tid] = 0;
    __syncthreads();
    const int b0 = cbase[cb], b1 = cbase[cb + 1];
    for (int i = b0 + tid; i < b1; i += 256) atomicAdd(&h[crel8[i]], 1);
    __syncthreads();
    int myv = (tid < 64) ? h[tid] : 0;
    ps[tid] = myv;
    __syncthreads();
    for (int off = 1; off < 64; off <<= 1) {
        int v = (tid >= off) ? ps[tid - off] : 0;
        __syncthreads();
        ps[tid] += v;
        __syncthreads();
    }
    if (tid < 64) {
        int excl = ps[tid] - myv;
        int n = node0 + tid;
        cur[tid] = b0 + excl;
        if (n < NN) {
            rowptr[n] = b0 + excl;
            dis[n] = rsqrtf((float)myv + 1.0f);  // +1 = self-loop
        }
    }
    __syncthreads();
    for (int i = b0 + tid; i < b1; i += 256) {
        int r = crel8[i];
        int pos = atomicAdd(&cur[r], 1);  // LDS atomic only
        entries[pos] = csrc16[i];
    }
}

// ---- xws = dis[n] * (x @ W1) -> bf16 [NN,32]; x is [NN,128] bf16 or fp32 ----
__global__ __launch_bounds__(256) void k_xw1(const void* __restrict__ xv, const void* __restrict__ W1v,
                                             const float* __restrict__ dis,
                                             const int* __restrict__ flag, u16* __restrict__ xwb) {
    __shared__ float wsm[FIN * HH];   // 16 KB
    __shared__ float xs[128][33];     // 16.9 KB
    const int f = *flag;
    const int tid = threadIdx.x;
    if (f) {
        const u16* W1 = (const u16*)W1v;
        for (int i = tid; i < FIN * HH; i += 256) wsm[i] = bf2f(W1[i]);
    } else {
        const float* W1 = (const float*)W1v;
        for (int i = tid; i < FIN * HH; i += 256) wsm[i] = W1[i];
    }
    const int n0 = blockIdx.x * 128;
    const int ct = tid & 7, rg = tid >> 3;
    const int lr = tid >> 1, lh = tid & 1;
    int ln = n0 + lr; if (ln >= NN) ln = NN - 1;
    float acc[4][4] = {};
    for (int kc = 0; kc < FIN; kc += 32) {
        __syncthreads();
        float* dq = &xs[lr][lh * 16];
        if (f) {
            const u16* lp = (const u16*)xv + (size_t)ln * FIN + lh * 16 + kc;
            uint4 a = *(const uint4*)lp;
            uint4 b = *(const uint4*)(lp + 8);
            u32 aw[4] = {a.x, a.y, a.z, a.w}, bw[4] = {b.x, b.y, b.z, b.w};
            #pragma unroll
            for (int i = 0; i < 4; ++i) {
                dq[2*i]     = bf2f((u16)(aw[i] & 0xffffu));
                dq[2*i+1]   = bf2f((u16)(aw[i] >> 16));
                dq[8+2*i]   = bf2f((u16)(bw[i] & 0xffffu));
                dq[8+2*i+1] = bf2f((u16)(bw[i] >> 16));
            }
        } else {
            const float* lp = (const float*)xv + (size_t)ln * FIN + lh * 16 + kc;
            #pragma unroll
            for (int i = 0; i < 4; ++i) {
                float4 t = *(const float4*)(lp + 4 * i);
                dq[4*i] = t.x; dq[4*i+1] = t.y; dq[4*i+2] = t.z; dq[4*i+3] = t.w;
            }
        }
        __syncthreads();
        #pragma unroll
        for (int k = 0; k < 32; ++k) {
            float4 wv = *(const float4*)&wsm[(kc + k) * HH + ct * 4];
            #pragma unroll
            for (int j = 0; j < 4; ++j) {
                float xvv = xs[rg * 4 + j][k];
                acc[j][0] = fmaf(xvv, wv.x, acc[j][0]);
                acc[j][1] = fmaf(xvv, wv.y, acc[j][1]);
                acc[j][2] = fmaf(xvv, wv.z, acc[j][2]);
                acc[j][3] = fmaf(xvv, wv.w, acc[j][3]);
            }
        }
    }
    #pragma unroll
    for (int j = 0; j < 4; ++j) {
        int n = n0 + rg * 4 + j;
        if (n < NN) {
            float dd = dis[n];
            ushort4 o;
            o.x = f2bf(dd * acc[j][0]); o.y = f2bf(dd * acc[j][1]);
            o.z = f2bf(dd * acc[j][2]); o.w = f2bf(dd * acc[j][3]);
            *(ushort4*)&xwb[(size_t)n * HH + ct * 4] = o;
        }
    }
}

// ---- xws = dis[n] * (h1 @ W2) -> bf16; h1 is bf16 [NN,32] (internal) ----
__global__ __launch_bounds__(256) void k_xw2(const u16* __restrict__ h1, const void* __restrict__ W2v,
                                             const float* __restrict__ dis,
                                             const int* __restrict__ flag, u16* __restrict__ xwb) {
    __shared__ float wsm[HH * HH];
    __shared__ float xs[128][33];
    const int f = *flag;
    const int tid = threadIdx.x;
    if (f) {
        const u16* W2 = (const u16*)W2v;
        for (int i = tid; i < HH * HH; i += 256) wsm[i] = bf2f(W2[i]);
    } else {
        const float* W2 = (const float*)W2v;
        for (int i = tid; i < HH * HH; i += 256) wsm[i] = W2[i];
    }
    const int n0 = blockIdx.x * 128;
    const int lr = tid >> 1, lh = tid & 1;
    int ln = n0 + lr; if (ln >= NN) ln = NN - 1;
    const u16* lp = h1 + (size_t)ln * HH + lh * 16;
    uint4 a = *(const uint4*)lp;
    uint4 b = *(const uint4*)(lp + 8);
    float* dq = &xs[lr][lh * 16];
    u32 aw[4] = {a.x, a.y, a.z, a.w}, bw[4] = {b.x, b.y, b.z, b.w};
    #pragma unroll
    for (int i = 0; i < 4; ++i) {
        dq[2*i]     = bf2f((u16)(aw[i] & 0xffffu));
        dq[2*i+1]   = bf2f((u16)(aw[i] >> 16));
        dq[8+2*i]   = bf2f((u16)(bw[i] & 0xffffu));
        dq[8+2*i+1] = bf2f((u16)(bw[i] >> 16));
    }
    __syncthreads();
    const int ct = tid & 7, rg = tid >> 3;
    float acc[4][4] = {};
    #pragma unroll
    for (int k = 0; k < 32; ++k) {
        float4 wv = *(const float4*)&wsm[k * HH + ct * 4];
        #pragma unroll
        for (int j = 0; j < 4; ++j) {
            float xv = xs[rg * 4 + j][k];
            acc[j][0] = fmaf(xv, wv.x, acc[j][0]);
            acc[j][1] = fmaf(xv, wv.y, acc[j][1]);
            acc[j][2] = fmaf(xv, wv.z, acc[j][2]);
            acc[j][3] = fmaf(xv, wv.w, acc[j][3]);
        }
    }
    #pragma unroll
    for (int j = 0; j < 4; ++j) {
        int n = n0 + rg * 4 + j;
        if (n < NN) {
            float dd = dis[n];
            ushort4 o;
            o.x = f2bf(dd * acc[j][0]); o.y = f2bf(dd * acc[j][1]);
            o.z = f2bf(dd * acc[j][2]); o.w = f2bf(dd * acc[j][3]);
            *(ushort4*)&xwb[(size_t)n * HH + ct * 4] = o;
        }
    }
}

// ---- CSR gather + fused epilogue: one node per 32-lane group ----
// xws rows are pre-scaled by dis[src]; self term is the scaled row itself.
// out[n] = tanh( dis[n] * ( xws[n] + sum_{s in N(n)} xws[s] ) + bias )
__global__ __launch_bounds__(256) void k_gather(const int* __restrict__ rowptr, const u16* __restrict__ entries,
                                                const u16* __restrict__ xws, const float* __restrict__ dis,
                                                const void* __restrict__ bv, const int* __restrict__ flag,
                                                int force16, u16* __restrict__ dst16, float* __restrict__ dst32) {
    const int f = *flag;
    int g = (blockIdx.x * 256 + threadIdx.x) >> 5;  // node
    int lane = threadIdx.x & 31;                    // channel
    if (g >= NN) return;
    float bias = f ? bf2f(((const u16*)bv)[lane]) : ((const float*)bv)[lane];
    const int beg = rowptr[g], end = rowptr[g + 1];
    const float dd = dis[g];
    float acc0 = bf2f(xws[(size_t)g * HH + lane]);  // self-loop (already scaled)
    float acc1 = 0.f, acc2 = 0.f, acc3 = 0.f;
    int i = beg;
    for (; i + 4 <= end; i += 4) {
        int s0 = entries[i], s1 = entries[i + 1], s2 = entries[i + 2], s3 = entries[i + 3];
        acc0 += bf2f(xws[(size_t)s0 * HH + lane]);
        acc1 += bf2f(xws[(size_t)s1 * HH + lane]);
        acc2 += bf2f(xws[(size_t)s2 * HH + lane]);
        acc3 += bf2f(xws[(size_t)s3 * HH + lane]);
    }
    for (; i < end; ++i) {
        acc0 += bf2f(xws[(size_t)entries[i] * HH + lane]);
    }
    float v = tanhf(fmaf(dd, (acc0 + acc1) + (acc2 + acc3), bias));
    size_t idx = (size_t)g * HH + lane;
    if (force16 | f) dst16[idx] = f2bf(v);
    else             dst32[idx] = v;
}

// ---- classifier: logits = h2 @ Wc + bc ----
__global__ __launch_bounds__(256) void k_cls(void* __restrict__ outbase, const void* __restrict__ Wcv,
                                             const void* __restrict__ bcv, const int* __restrict__ flag) {
    __shared__ float wsm[HH * CC];
    __shared__ float bs[CC];
    const int f = *flag;
    int tid = threadIdx.x;
    if (f) {
        const u16* Wc = (const u16*)Wcv;
        for (int i = tid; i < HH * CC; i += 256) wsm[i] = bf2f(Wc[i]);
        if (tid < CC) bs[tid] = bf2f(((const u16*)bcv)[tid]);
    } else {
        const float* Wc = (const float*)Wcv;
        for (int i = tid; i < HH * CC; i += 256) wsm[i] = Wc[i];
        if (tid < CC) bs[tid] = ((const float*)bcv)[tid];
    }
    __syncthreads();
    int t = blockIdx.x * 256 + tid;
    int n = t >> 4;
    if (n < NN) {
        int cl = t & 15;
        float acc = bs[cl];
        if (f) {
            const u16* r = (const u16*)outbase + (size_t)NN * CC + (size_t)n * HH;
            #pragma unroll
            for (int k = 0; k < HH; ++k) acc = fmaf(bf2f(r[k]), wsm[k * CC + cl], acc);
            ((u16*)outbase)[t] = f2bf(acc);
        } else {
            const float* r = (const float*)outbase + (size_t)NN * CC + (size_t)n * HH;
            #pragma unroll
            for (int k = 0; k < HH; ++k) acc = fmaf(r[k], wsm[k * CC + cl], acc);
            ((float*)outbase)[t] = acc;
        }
    }
}

extern "C" void kernel_launch(void* const* d_in, const int* in_sizes, int n_in,
                              void* d_out, int out_size, void* d_ws, size_t ws_size,
                              hipStream_t stream) {
    const void* x  = d_in[0];
    const int*  ei = (const int*)d_in[1];
    const void* W1 = d_in[2];
    const void* b1 = d_in[3];
    const void* W2 = d_in[4];
    const void* b2 = d_in[5];
    const void* Wc = d_in[6];
    const void* bc = d_in[7];
    const int* srcv = ei;
    const int* dstv = ei + EE;

    // ws layout (bytes), total ~7.44 MB:
    //   [0, 4096)            flag
    //   [4096, 208896)       rowptr int[N+1]
    //   [208896, 413696)     dis f32[N]
    //   [413696, 417792)     cbase int[NB+1]
    //   [417792, 421888)     btot int[NB]
    //   [421888, 1036288)    hist_g int[NBLK*NB] (613 KB)
    //   [1036288, 4236288)   xwb  bf16[N*32]
    //   [4236288, 7436288)   entries u16[E]
    char*  ws     = (char*)d_ws;
    int*   flag   = (int*)ws;
    int*   rowptr = (int*)(ws + 4096);
    float* dis    = (float*)(ws + 208896);
    int*   cbase  = (int*)(ws + 413696);
    int*   btot   = (int*)(ws + 417792);
    int*   hist_g = (int*)(ws + 421888);
    u16*   xwb    = (u16*)(ws + 1036288);
    u16*   entries= (u16*)(ws + 4236288);

    // Coarse-grouped temporaries live in d_out's head (consumed before h1 is
    // written there). csrc16: 3.2 MB, crel8: 1.6 MB -> 4.8 MB = min(out_size).
    u16*   csrc16 = (u16*)d_out;
    u8*    crel8  = (u8*)d_out + (size_t)EE * 2;

    // h1 (bf16, internal) lives in d_out's head; h2 goes to its final slot.
    u16*   h1    = (u16*)d_out;
    u16*   h2_16 = (u16*)d_out + (size_t)NN * CC;
    float* h2_32 = (float*)d_out + (size_t)NN * CC;

    k_probe<<<1, 256, 0, stream>>>((const u32*)x, flag);

    // deterministic two-level CSR build (zero global atomics, no big
    // single-block passes: only k_cscan is single-block, over 3 KB)
    k_hist<<<NBLK, 256, 0, stream>>>(dstv, hist_g);
    k_rscan<<<NB, 256, 0, stream>>>(hist_g, btot);
    k_cscan<<<1, 1024, 0, stream>>>(btot, cbase, rowptr);
    k_place<<<NBLK, 256, 0, stream>>>(srcv, dstv, hist_g, cbase, csrc16, crel8);
    k_fine<<<NB, 256, 0, stream>>>(cbase, nullptr, csrc16, crel8, rowptr, dis, entries);

    // layer 1: xws1 (dis-scaled) -> gather (fused agg+bias+tanh) -> h1 (bf16)
    k_xw1<<<(NN + 127) / 128, 256, 0, stream>>>(x, W1, dis, flag, xwb);
    k_gather<<<((NN * 32) + 255) / 256, 256, 0, stream>>>(rowptr, entries, xwb, dis, b1, flag,
                                                          1, h1, (float*)nullptr);

    // layer 2: xws2 (reads h1) -> gather -> h2 (final slot, dtype per flag)
    k_xw2<<<(NN + 127) / 128, 256, 0, stream>>>(h1, W2, dis, flag, xwb);
    k_gather<<<((NN * 32) + 255) / 256, 256, 0, stream>>>(rowptr, entries, xwb, dis, b2, flag,
                                                          0, h2_16, h2_32);

    // classifier
    k_cls<<<(NN * CC + 255) / 256, 256, 0, stream>>>(d_out, Wc, bc, flag);
}

// Round 5
// 214.101 us; speedup vs baseline: 6.1920x; 1.0932x over previous
//
#include <hip/hip_runtime.h>
#include <hip/hip_bf16.h>

#define NN 50000
#define EE 1600000
#define FIN 128
#define HH 32
#define CC 16
#define NB 782        // ceil(NN/64) coarse dst-buckets of 64 nodes
#define NBLK 391      // edge-chunk blocks: 391 * 4096 >= EE
#define CHUNK 4096

typedef unsigned short u16;
typedef unsigned int u32;
typedef unsigned char u8;

__device__ __forceinline__ float bf2f(u16 u) {
    union { u32 i; float f; } v; v.i = ((u32)u) << 16; return v.f;
}
__device__ __forceinline__ u16 f2bf(float f) {
    union { float f; u32 i; } v; v.f = f;
    u32 x = v.i;
    return (u16)((x + 0x7fffu + ((x >> 16) & 1u)) >> 16);  // RNE
}

// ---- dtype probe: flag=1 if float tensors are bf16, 0 if fp32 ----
__global__ __launch_bounds__(256) void k_probe(const u32* __restrict__ xw_words, int* __restrict__ flag) {
    __shared__ int cs;
    if (threadIdx.x == 0) cs = 0;
    __syncthreads();
    int c = 0;
    for (int i = threadIdx.x; i < 512; i += 256) {
        float v = fabsf(bf2f((u16)(xw_words[i] & 0xffffu)));
        if (v >= 6.0e-8f && v <= 64.0f) c++;
    }
    atomicAdd(&cs, c);
    __syncthreads();
    if (threadIdx.x == 0) *flag = (cs > 384) ? 1 : 0;
}

// ---- block-major coarse sort: each block LDS-sorts its chunk by dst>>6 and
//      streams (src16, rel8) to its PRIVATE contiguous region. Also emits
//      locT[cb][b] = local exclusive offset of bucket cb within chunk b. ----
__global__ __launch_bounds__(256) void k_place(const int* __restrict__ src, const int* __restrict__ dst,
                                               int* __restrict__ locT,
                                               u16* __restrict__ gsrc, u8* __restrict__ grel) {
    __shared__ int dst_s[CHUNK];      // 16 KB
    __shared__ u16 s_src[CHUNK];      // 8 KB
    __shared__ u8  s_rel[CHUNK];      // 4 KB
    __shared__ int cur[NB];           // 3.1 KB (histogram -> cursors)
    __shared__ int ps[256];           // 1 KB
    const int tid = threadIdx.x, blk = blockIdx.x;
    const int e0 = blk * CHUNK;
    int cnt = EE - e0; if (cnt > CHUNK) cnt = CHUNK;   // cnt % 4 == 0 always

    // stage dst chunk (coalesced uint4)
    const uint4* gd4 = (const uint4*)(dst + e0);
    for (int i = tid; i < cnt / 4; i += 256) ((uint4*)dst_s)[i] = gd4[i];
    for (int i = tid; i < NB; i += 256) cur[i] = 0;
    __syncthreads();

    // LDS histogram of dst>>6
    for (int k = 0; k < CHUNK / 256; ++k) {
        int i = k * 256 + tid;
        if (i < cnt) atomicAdd(&cur[dst_s[i] >> 6], 1);
    }
    __syncthreads();

    // exclusive scan over 782 bins (4 bins/thread + 256-wide scan)
    const int bi = tid * 4;
    int v0 = 0, v1 = 0, v2 = 0, v3 = 0;
    if (bi < NB)     v0 = cur[bi];
    if (bi + 1 < NB) v1 = cur[bi + 1];
    if (bi + 2 < NB) v2 = cur[bi + 2];
    if (bi + 3 < NB) v3 = cur[bi + 3];
    ps[tid] = v0 + v1 + v2 + v3;
    __syncthreads();
    for (int off = 1; off < 256; off <<= 1) {
        int t = (tid >= off) ? ps[tid - off] : 0;
        __syncthreads();
        ps[tid] += t;
        __syncthreads();
    }
    int run = (tid == 0) ? 0 : ps[tid - 1];
    if (bi < NB)     { cur[bi] = run;     locT[(size_t)bi * NBLK + blk] = run;     run += v0; }
    if (bi + 1 < NB) { cur[bi + 1] = run; locT[(size_t)(bi + 1) * NBLK + blk] = run; run += v1; }
    if (bi + 2 < NB) { cur[bi + 2] = run; locT[(size_t)(bi + 2) * NBLK + blk] = run; run += v2; }
    if (bi + 3 < NB) { cur[bi + 3] = run; locT[(size_t)(bi + 3) * NBLK + blk] = run; run += v3; }
    if (tid == 255) locT[(size_t)NB * NBLK + blk] = ps[255];  // chunk total
    __syncthreads();

    // counting-sort into LDS (src read coalesced from global)
    for (int k = 0; k < CHUNK / 256; ++k) {
        int i = k * 256 + tid;
        if (i < cnt) {
            int d = dst_s[i];
            int pos = atomicAdd(&cur[d >> 6], 1);  // LDS atomic only
            s_src[pos] = (u16)src[e0 + i];
            s_rel[pos] = (u8)(d & 63);
        }
    }
    __syncthreads();

    // stream out to private region (fully coalesced dwordx4)
    const uint4* ss = (const uint4*)s_src;
    uint4* gs = (uint4*)(gsrc + (size_t)blk * CHUNK);
    for (int i = tid; i < (cnt * 2) / 16; i += 256) gs[i] = ss[i];
    const uint4* sr = (const uint4*)s_rel;
    uint4* gr = (uint4*)(grel + (size_t)blk * CHUNK);
    for (int i = tid; i < cnt / 16; i += 256) gr[i] = sr[i];
}

// ---- bucket totals from locT rows (coalesced) ----
__global__ __launch_bounds__(256) void k_btot(const int* __restrict__ locT, int* __restrict__ btot) {
    __shared__ int ps[256];
    const int cb = blockIdx.x;
    int s = 0;
    for (int b = threadIdx.x; b < NBLK; b += 256)
        s += locT[(size_t)(cb + 1) * NBLK + b] - locT[(size_t)cb * NBLK + b];
    ps[threadIdx.x] = s;
    __syncthreads();
    for (int off = 128; off > 0; off >>= 1) {
        if (threadIdx.x < off) ps[threadIdx.x] += ps[threadIdx.x + off];
        __syncthreads();
    }
    if (threadIdx.x == 0) btot[cb] = ps[0];
}

// ---- tiny single-block scan over bucket totals (3 KB only) ----
__global__ __launch_bounds__(1024) void k_cscan(const int* __restrict__ btot, int* __restrict__ cbase,
                                                int* __restrict__ rowptr) {
    __shared__ int ps[1024];
    const int t = threadIdx.x;
    int myv = (t < NB) ? btot[t] : 0;
    ps[t] = myv;
    __syncthreads();
    for (int off = 1; off < 1024; off <<= 1) {
        int v = (t >= off) ? ps[t - off] : 0;
        __syncthreads();
        ps[t] += v;
        __syncthreads();
    }
    if (t < NB) cbase[t] = ps[t] - myv;  // exclusive
    if (t == 0) { cbase[NB] = EE; rowptr[NN] = EE; }
}

// ---- fused fine stage (per bucket): flatten 391 micro-ranges, count 64 bins,
//      local scan, write rowptr + dis, regroup entries by exact node. ----
__global__ __launch_bounds__(256) void k_fine(const int* __restrict__ locT, const int* __restrict__ cbase,
                                              const u16* __restrict__ gsrc, const u8* __restrict__ grel,
                                              int* __restrict__ rowptr, float* __restrict__ dis,
                                              u16* __restrict__ entries) {
    __shared__ int beg_s[NBLK];
    __shared__ int fo[NBLK + 1];
    __shared__ int ps[256];
    __shared__ int h[64];
    __shared__ int cur[64];
    const int tid = threadIdx.x, cb = blockIdx.x;

    for (int b = tid; b < NBLK; b += 256) {
        int beg = locT[(size_t)cb * NBLK + b];
        beg_s[b] = beg;
        fo[b] = locT[(size_t)(cb + 1) * NBLK + b] - beg;  // len
    }
    if (tid < 64) h[tid] = 0;
    __syncthreads();

    // exclusive scan of fo[0..NBLK) (2 elems/thread)
    const int b0 = tid * 2;
    int a = (b0 < NBLK) ? fo[b0] : 0;
    int b1v = (b0 + 1 < NBLK) ? fo[b0 + 1] : 0;
    ps[tid] = a + b1v;
    __syncthreads();
    for (int off = 1; off < 256; off <<= 1) {
        int v = (tid >= off) ? ps[tid - off] : 0;
        __syncthreads();
        ps[tid] += v;
        __syncthreads();
    }
    int run = (tid == 0) ? 0 : ps[tid - 1];
    if (b0 < NBLK)     { fo[b0] = run;     run += a; }
    if (b0 + 1 < NBLK) { fo[b0 + 1] = run; run += b1v; }
    if (tid == 255) fo[NBLK] = ps[255];  // total T
    __syncthreads();
    const int T = fo[NBLK];

    // pass 1: fine histogram
    for (int i = tid; i < T; i += 256) {
        int lo = 0, hi = NBLK;
        while (hi - lo > 1) { int mid = (lo + hi) >> 1; if (fo[mid] <= i) lo = mid; else hi = mid; }
        int g = lo * CHUNK + beg_s[lo] + (i - fo[lo]);
        atomicAdd(&h[grel[g]], 1);
    }
    __syncthreads();

    // 64-wide scan -> rowptr, dis, cursors
    const int node0 = cb * 64;
    const int base = cbase[cb];
    int myv = (tid < 64) ? h[tid] : 0;
    ps[tid] = (tid < 64) ? myv : 0;
    __syncthreads();
    for (int off = 1; off < 64; off <<= 1) {
        int v = (tid >= off && tid < 64) ? ps[tid - off] : 0;
        __syncthreads();
        if (tid < 64) ps[tid] += v;
        __syncthreads();
    }
    if (tid < 64) {
        int excl = ps[tid] - myv;
        int n = node0 + tid;
        cur[tid] = base + excl;
        if (n < NN) {
            rowptr[n] = base + excl;
            dis[n] = rsqrtf((float)myv + 1.0f);  // +1 = self-loop
        }
    }
    __syncthreads();

    // pass 2: place entries (private region [base, base+T))
    for (int i = tid; i < T; i += 256) {
        int lo = 0, hi = NBLK;
        while (hi - lo > 1) { int mid = (lo + hi) >> 1; if (fo[mid] <= i) lo = mid; else hi = mid; }
        int g = lo * CHUNK + beg_s[lo] + (i - fo[lo]);
        int r = grel[g];
        int pos = atomicAdd(&cur[r], 1);  // LDS atomic only
        entries[pos] = gsrc[g];
    }
}

// ---- xws = dis[n] * (x @ W1) -> bf16 [NN,32]; x is [NN,128] bf16 or fp32 ----
__global__ __launch_bounds__(256) void k_xw1(const void* __restrict__ xv, const void* __restrict__ W1v,
                                             const float* __restrict__ dis,
                                             const int* __restrict__ flag, u16* __restrict__ xwb) {
    __shared__ float wsm[FIN * HH];   // 16 KB
    __shared__ float xs[128][33];     // 16.9 KB
    const int f = *flag;
    const int tid = threadIdx.x;
    if (f) {
        const u16* W1 = (const u16*)W1v;
        for (int i = tid; i < FIN * HH; i += 256) wsm[i] = bf2f(W1[i]);
    } else {
        const float* W1 = (const float*)W1v;
        for (int i = tid; i < FIN * HH; i += 256) wsm[i] = W1[i];
    }
    const int n0 = blockIdx.x * 128;
    const int ct = tid & 7, rg = tid >> 3;
    const int lr = tid >> 1, lh = tid & 1;
    int ln = n0 + lr; if (ln >= NN) ln = NN - 1;
    float acc[4][4] = {};
    for (int kc = 0; kc < FIN; kc += 32) {
        __syncthreads();
        float* dq = &xs[lr][lh * 16];
        if (f) {
            const u16* lp = (const u16*)xv + (size_t)ln * FIN + lh * 16 + kc;
            uint4 a = *(const uint4*)lp;
            uint4 b = *(const uint4*)(lp + 8);
            u32 aw[4] = {a.x, a.y, a.z, a.w}, bw[4] = {b.x, b.y, b.z, b.w};
            #pragma unroll
            for (int i = 0; i < 4; ++i) {
                dq[2*i]     = bf2f((u16)(aw[i] & 0xffffu));
                dq[2*i+1]   = bf2f((u16)(aw[i] >> 16));
                dq[8+2*i]   = bf2f((u16)(bw[i] & 0xffffu));
                dq[8+2*i+1] = bf2f((u16)(bw[i] >> 16));
            }
        } else {
            const float* lp = (const float*)xv + (size_t)ln * FIN + lh * 16 + kc;
            #pragma unroll
            for (int i = 0; i < 4; ++i) {
                float4 t = *(const float4*)(lp + 4 * i);
                dq[4*i] = t.x; dq[4*i+1] = t.y; dq[4*i+2] = t.z; dq[4*i+3] = t.w;
            }
        }
        __syncthreads();
        #pragma unroll
        for (int k = 0; k < 32; ++k) {
            float4 wv = *(const float4*)&wsm[(kc + k) * HH + ct * 4];
            #pragma unroll
            for (int j = 0; j < 4; ++j) {
                float xvv = xs[rg * 4 + j][k];
                acc[j][0] = fmaf(xvv, wv.x, acc[j][0]);
                acc[j][1] = fmaf(xvv, wv.y, acc[j][1]);
                acc[j][2] = fmaf(xvv, wv.z, acc[j][2]);
                acc[j][3] = fmaf(xvv, wv.w, acc[j][3]);
            }
        }
    }
    #pragma unroll
    for (int j = 0; j < 4; ++j) {
        int n = n0 + rg * 4 + j;
        if (n < NN) {
            float dd = dis[n];
            ushort4 o;
            o.x = f2bf(dd * acc[j][0]); o.y = f2bf(dd * acc[j][1]);
            o.z = f2bf(dd * acc[j][2]); o.w = f2bf(dd * acc[j][3]);
            *(ushort4*)&xwb[(size_t)n * HH + ct * 4] = o;
        }
    }
}

// ---- xws = dis[n] * (h1 @ W2) -> bf16; h1 is bf16 [NN,32] (internal) ----
__global__ __launch_bounds__(256) void k_xw2(const u16* __restrict__ h1, const void* __restrict__ W2v,
                                             const float* __restrict__ dis,
                                             const int* __restrict__ flag, u16* __restrict__ xwb) {
    __shared__ float wsm[HH * HH];
    __shared__ float xs[128][33];
    const int f = *flag;
    const int tid = threadIdx.x;
    if (f) {
        const u16* W2 = (const u16*)W2v;
        for (int i = tid; i < HH * HH; i += 256) wsm[i] = bf2f(W2[i]);
    } else {
        const float* W2 = (const float*)W2v;
        for (int i = tid; i < HH * HH; i += 256) wsm[i] = W2[i];
    }
    const int n0 = blockIdx.x * 128;
    const int lr = tid >> 1, lh = tid & 1;
    int ln = n0 + lr; if (ln >= NN) ln = NN - 1;
    const u16* lp = h1 + (size_t)ln * HH + lh * 16;
    uint4 a = *(const uint4*)lp;
    uint4 b = *(const uint4*)(lp + 8);
    float* dq = &xs[lr][lh * 16];
    u32 aw[4] = {a.x, a.y, a.z, a.w}, bw[4] = {b.x, b.y, b.z, b.w};
    #pragma unroll
    for (int i = 0; i < 4; ++i) {
        dq[2*i]     = bf2f((u16)(aw[i] & 0xffffu));
        dq[2*i+1]   = bf2f((u16)(aw[i] >> 16));
        dq[8+2*i]   = bf2f((u16)(bw[i] & 0xffffu));
        dq[8+2*i+1] = bf2f((u16)(bw[i] >> 16));
    }
    __syncthreads();
    const int ct = tid & 7, rg = tid >> 3;
    float acc[4][4] = {};
    #pragma unroll
    for (int k = 0; k < 32; ++k) {
        float4 wv = *(const float4*)&wsm[k * HH + ct * 4];
        #pragma unroll
        for (int j = 0; j < 4; ++j) {
            float xv = xs[rg * 4 + j][k];
            acc[j][0] = fmaf(xv, wv.x, acc[j][0]);
            acc[j][1] = fmaf(xv, wv.y, acc[j][1]);
            acc[j][2] = fmaf(xv, wv.z, acc[j][2]);
            acc[j][3] = fmaf(xv, wv.w, acc[j][3]);
        }
    }
    #pragma unroll
    for (int j = 0; j < 4; ++j) {
        int n = n0 + rg * 4 + j;
        if (n < NN) {
            float dd = dis[n];
            ushort4 o;
            o.x = f2bf(dd * acc[j][0]); o.y = f2bf(dd * acc[j][1]);
            o.z = f2bf(dd * acc[j][2]); o.w = f2bf(dd * acc[j][3]);
            *(ushort4*)&xwb[(size_t)n * HH + ct * 4] = o;
        }
    }
}

// ---- CSR gather + fused epilogue: one node per 32-lane group ----
// xws rows are pre-scaled by dis[src]; self term is the scaled row itself.
// out[n] = tanh( dis[n] * ( xws[n] + sum_{s in N(n)} xws[s] ) + bias )
__global__ __launch_bounds__(256) void k_gather(const int* __restrict__ rowptr, const u16* __restrict__ entries,
                                                const u16* __restrict__ xws, const float* __restrict__ dis,
                                                const void* __restrict__ bv, const int* __restrict__ flag,
                                                int force16, u16* __restrict__ dst16, float* __restrict__ dst32) {
    const int f = *flag;
    int g = (blockIdx.x * 256 + threadIdx.x) >> 5;  // node
    int lane = threadIdx.x & 31;                    // channel
    if (g >= NN) return;
    float bias = f ? bf2f(((const u16*)bv)[lane]) : ((const float*)bv)[lane];
    const int beg = rowptr[g], end = rowptr[g + 1];
    const float dd = dis[g];
    float acc0 = bf2f(xws[(size_t)g * HH + lane]);  // self-loop (already scaled)
    float acc1 = 0.f, acc2 = 0.f, acc3 = 0.f;
    int i = beg;
    for (; i + 4 <= end; i += 4) {
        int s0 = entries[i], s1 = entries[i + 1], s2 = entries[i + 2], s3 = entries[i + 3];
        acc0 += bf2f(xws[(size_t)s0 * HH + lane]);
        acc1 += bf2f(xws[(size_t)s1 * HH + lane]);
        acc2 += bf2f(xws[(size_t)s2 * HH + lane]);
        acc3 += bf2f(xws[(size_t)s3 * HH + lane]);
    }
    for (; i < end; ++i) {
        acc0 += bf2f(xws[(size_t)entries[i] * HH + lane]);
    }
    float v = tanhf(fmaf(dd, (acc0 + acc1) + (acc2 + acc3), bias));
    size_t idx = (size_t)g * HH + lane;
    if (force16 | f) dst16[idx] = f2bf(v);
    else             dst32[idx] = v;
}

// ---- classifier: logits = h2 @ Wc + bc ----
__global__ __launch_bounds__(256) void k_cls(void* __restrict__ outbase, const void* __restrict__ Wcv,
                                             const void* __restrict__ bcv, const int* __restrict__ flag) {
    __shared__ float wsm[HH * CC];
    __shared__ float bs[CC];
    const int f = *flag;
    int tid = threadIdx.x;
    if (f) {
        const u16* Wc = (const u16*)Wcv;
        for (int i = tid; i < HH * CC; i += 256) wsm[i] = bf2f(Wc[i]);
        if (tid < CC) bs[tid] = bf2f(((const u16*)bcv)[tid]);
    } else {
        const float* Wc = (const float*)Wcv;
        for (int i = tid; i < HH * CC; i += 256) wsm[i] = Wc[i];
        if (tid < CC) bs[tid] = ((const float*)bcv)[tid];
    }
    __syncthreads();
    int t = blockIdx.x * 256 + tid;
    int n = t >> 4;
    if (n < NN) {
        int cl = t & 15;
        float acc = bs[cl];
        if (f) {
            const u16* r = (const u16*)outbase + (size_t)NN * CC + (size_t)n * HH;
            #pragma unroll
            for (int k = 0; k < HH; ++k) acc = fmaf(bf2f(r[k]), wsm[k * CC + cl], acc);
            ((u16*)outbase)[t] = f2bf(acc);
        } else {
            const float* r = (const float*)outbase + (size_t)NN * CC + (size_t)n * HH;
            #pragma unroll
            for (int k = 0; k < HH; ++k) acc = fmaf(r[k], wsm[k * CC + cl], acc);
            ((float*)outbase)[t] = acc;
        }
    }
}

extern "C" void kernel_launch(void* const* d_in, const int* in_sizes, int n_in,
                              void* d_out, int out_size, void* d_ws, size_t ws_size,
                              hipStream_t stream) {
    const void* x  = d_in[0];
    const int*  ei = (const int*)d_in[1];
    const void* W1 = d_in[2];
    const void* b1 = d_in[3];
    const void* W2 = d_in[4];
    const void* b2 = d_in[5];
    const void* Wc = d_in[6];
    const void* bc = d_in[7];
    const int* srcv = ei;
    const int* dstv = ei + EE;

    // ws layout (bytes), total ~8.05 MB (8.42 MB proven in round-2 run):
    //   [0, 4096)            flag
    //   [4096, 208896)       rowptr int[N+1]
    //   [208896, 413696)     dis f32[N]
    //   [413696, 417792)     cbase int[NB+1]
    //   [417792, 421888)     btot int[NB]
    //   [421888, 1646500)    locT int[(NB+1)*NBLK] (1.22 MB)
    //   [1646592, 4846592)   xwb  bf16[N*32]
    //   [4846592, 8046592)   entries u16[E]
    char*  ws     = (char*)d_ws;
    int*   flag   = (int*)ws;
    int*   rowptr = (int*)(ws + 4096);
    float* dis    = (float*)(ws + 208896);
    int*   cbase  = (int*)(ws + 413696);
    int*   btot   = (int*)(ws + 417792);
    int*   locT   = (int*)(ws + 421888);
    u16*   xwb    = (u16*)(ws + 1646592);
    u16*   entries= (u16*)(ws + 4846592);

    // Coarse-sorted chunks live in d_out's head (consumed by k_fine before h1
    // is written there). gsrc: EE*2 = 3.2 MB, grel: EE*1 = 1.6 MB -> 4.8 MB.
    u16*   gsrc = (u16*)d_out;
    u8*    grel = (u8*)d_out + (size_t)EE * 2;

    // h1 (bf16, internal) lives in d_out's head; h2 goes to its final slot.
    u16*   h1    = (u16*)d_out;
    u16*   h2_16 = (u16*)d_out + (size_t)NN * CC;
    float* h2_32 = (float*)d_out + (size_t)NN * CC;

    k_probe<<<1, 256, 0, stream>>>((const u32*)x, flag);

    // deterministic CSR build: block-major LDS counting-sort (private
    // coalesced writes), then per-bucket fine regroup. Zero global atomics.
    k_place<<<NBLK, 256, 0, stream>>>(srcv, dstv, locT, gsrc, grel);
    k_btot<<<NB, 256, 0, stream>>>(locT, btot);
    k_cscan<<<1, 1024, 0, stream>>>(btot, cbase, rowptr);
    k_fine<<<NB, 256, 0, stream>>>(locT, cbase, gsrc, grel, rowptr, dis, entries);

    // layer 1: xws1 (dis-scaled) -> gather (fused agg+bias+tanh) -> h1 (bf16)
    k_xw1<<<(NN + 127) / 128, 256, 0, stream>>>(x, W1, dis, flag, xwb);
    k_gather<<<((NN * 32) + 255) / 256, 256, 0, stream>>>(rowptr, entries, xwb, dis, b1, flag,
                                                          1, h1, (float*)nullptr);

    // layer 2: xws2 (reads h1) -> gather -> h2 (final slot, dtype per flag)
    k_xw2<<<(NN + 127) / 128, 256, 0, stream>>>(h1, W2, dis, flag, xwb);
    k_gather<<<((NN * 32) + 255) / 256, 256, 0, stream>>>(rowptr, entries, xwb, dis, b2, flag,
                                                          0, h2_16, h2_32);

    // classifier
    k_cls<<<(NN * CC + 255) / 256, 256, 0, stream>>>(d_out, Wc, bc, flag);
}

// Round 6
// 193.321 us; speedup vs baseline: 6.8576x; 1.1075x over previous
//
#include <hip/hip_runtime.h>
#include <hip/hip_bf16.h>

#define NN 50000
#define EE 1600000
#define FIN 128
#define HH 32
#define CC 16
#define NB 782        // ceil(NN/64) coarse dst-buckets of 64 nodes
#define NBLK 391      // edge-chunk blocks: 391 * 4096 >= EE
#define CHUNK 4096

typedef unsigned short u16;
typedef unsigned int u32;
typedef unsigned char u8;

__device__ __forceinline__ float bf2f(u16 u) {
    union { u32 i; float f; } v; v.i = ((u32)u) << 16; return v.f;
}
__device__ __forceinline__ u16 f2bf(float f) {
    union { float f; u32 i; } v; v.f = f;
    u32 x = v.i;
    return (u16)((x + 0x7fffu + ((x >> 16) & 1u)) >> 16);  // RNE
}

// ---- block-major coarse sort: each block LDS-sorts its chunk by dst>>6 and
//      streams (src16, rel8) to its PRIVATE contiguous region. Also emits
//      locT[cb][b] = local exclusive offset of bucket cb within chunk b. ----
__global__ __launch_bounds__(256) void k_place(const int* __restrict__ src, const int* __restrict__ dst,
                                               int* __restrict__ locT,
                                               u16* __restrict__ gsrc, u8* __restrict__ grel) {
    __shared__ int dst_s[CHUNK];      // 16 KB
    __shared__ u16 s_src[CHUNK];      // 8 KB
    __shared__ u8  s_rel[CHUNK];      // 4 KB
    __shared__ int cur[NB];           // 3.1 KB (histogram -> cursors)
    __shared__ int ps[256];           // 1 KB
    const int tid = threadIdx.x, blk = blockIdx.x;
    const int e0 = blk * CHUNK;
    int cnt = EE - e0; if (cnt > CHUNK) cnt = CHUNK;   // cnt % 16 == 0 always

    // stage dst chunk (coalesced uint4)
    const uint4* gd4 = (const uint4*)(dst + e0);
    for (int i = tid; i < cnt / 4; i += 256) ((uint4*)dst_s)[i] = gd4[i];
    for (int i = tid; i < NB; i += 256) cur[i] = 0;
    __syncthreads();

    // LDS histogram of dst>>6
    for (int k = 0; k < CHUNK / 256; ++k) {
        int i = k * 256 + tid;
        if (i < cnt) atomicAdd(&cur[dst_s[i] >> 6], 1);
    }
    __syncthreads();

    // exclusive scan over 782 bins (4 bins/thread + 256-wide scan)
    const int bi = tid * 4;
    int v0 = 0, v1 = 0, v2 = 0, v3 = 0;
    if (bi < NB)     v0 = cur[bi];
    if (bi + 1 < NB) v1 = cur[bi + 1];
    if (bi + 2 < NB) v2 = cur[bi + 2];
    if (bi + 3 < NB) v3 = cur[bi + 3];
    ps[tid] = v0 + v1 + v2 + v3;
    __syncthreads();
    for (int off = 1; off < 256; off <<= 1) {
        int t = (tid >= off) ? ps[tid - off] : 0;
        __syncthreads();
        ps[tid] += t;
        __syncthreads();
    }
    int run = (tid == 0) ? 0 : ps[tid - 1];
    if (bi < NB)     { cur[bi] = run;     locT[(size_t)bi * NBLK + blk] = run;     run += v0; }
    if (bi + 1 < NB) { cur[bi + 1] = run; locT[(size_t)(bi + 1) * NBLK + blk] = run; run += v1; }
    if (bi + 2 < NB) { cur[bi + 2] = run; locT[(size_t)(bi + 2) * NBLK + blk] = run; run += v2; }
    if (bi + 3 < NB) { cur[bi + 3] = run; locT[(size_t)(bi + 3) * NBLK + blk] = run; run += v3; }
    if (tid == 255) locT[(size_t)NB * NBLK + blk] = ps[255];  // chunk total
    __syncthreads();

    // counting-sort into LDS (src read coalesced from global)
    for (int k = 0; k < CHUNK / 256; ++k) {
        int i = k * 256 + tid;
        if (i < cnt) {
            int d = dst_s[i];
            int pos = atomicAdd(&cur[d >> 6], 1);  // LDS atomic only
            s_src[pos] = (u16)src[e0 + i];
            s_rel[pos] = (u8)(d & 63);
        }
    }
    __syncthreads();

    // stream out to private region (fully coalesced dwordx4)
    const uint4* ss = (const uint4*)s_src;
    uint4* gs = (uint4*)(gsrc + (size_t)blk * CHUNK);
    for (int i = tid; i < (cnt * 2) / 16; i += 256) gs[i] = ss[i];
    const uint4* sr = (const uint4*)s_rel;
    uint4* gr = (uint4*)(grel + (size_t)blk * CHUNK);
    for (int i = tid; i < cnt / 16; i += 256) gr[i] = sr[i];
}

// ---- bucket totals from locT rows (coalesced) ----
__global__ __launch_bounds__(256) void k_btot(const int* __restrict__ locT, int* __restrict__ btot) {
    __shared__ int ps[256];
    const int cb = blockIdx.x;
    int s = 0;
    for (int b = threadIdx.x; b < NBLK; b += 256)
        s += locT[(size_t)(cb + 1) * NBLK + b] - locT[(size_t)cb * NBLK + b];
    ps[threadIdx.x] = s;
    __syncthreads();
    for (int off = 128; off > 0; off >>= 1) {
        if (threadIdx.x < off) ps[threadIdx.x] += ps[threadIdx.x + off];
        __syncthreads();
    }
    if (threadIdx.x == 0) btot[cb] = ps[0];
}

// ---- single-block: dtype probe + scan over bucket totals (3 KB) ----
__global__ __launch_bounds__(1024) void k_cscan(const int* __restrict__ btot, int* __restrict__ cbase,
                                                int* __restrict__ rowptr,
                                                const u32* __restrict__ xw_words, int* __restrict__ flag) {
    __shared__ int ps[1024];
    __shared__ int cs;
    const int t = threadIdx.x;
    if (t == 0) cs = 0;
    __syncthreads();
    if (t < 512) {
        float v = fabsf(bf2f((u16)(xw_words[t] & 0xffffu)));
        if (v >= 6.0e-8f && v <= 64.0f) atomicAdd(&cs, 1);
    }
    int myv = (t < NB) ? btot[t] : 0;
    ps[t] = myv;
    __syncthreads();
    for (int off = 1; off < 1024; off <<= 1) {
        int v = (t >= off) ? ps[t - off] : 0;
        __syncthreads();
        ps[t] += v;
        __syncthreads();
    }
    if (t < NB) cbase[t] = ps[t] - myv;  // exclusive
    if (t == 0) {
        cbase[NB] = EE; rowptr[NN] = EE;
        *flag = (cs > 384) ? 1 : 0;      // bf16 data -> sane exponents ~100%
    }
}

// ---- fused fine stage (per bucket): per-thread micro-range walk (no binary
//      search), count 64 bins, local scan, write rowptr + dis, regroup. ----
__global__ __launch_bounds__(256) void k_fine(const int* __restrict__ locT, const int* __restrict__ cbase,
                                              const u16* __restrict__ gsrc, const u8* __restrict__ grel,
                                              int* __restrict__ rowptr, float* __restrict__ dis,
                                              u16* __restrict__ entries) {
    __shared__ int beg_s[NBLK];
    __shared__ int len_s[NBLK];
    __shared__ int ps[256];
    __shared__ int h[64];
    __shared__ int cur[64];
    const int tid = threadIdx.x, cb = blockIdx.x;

    for (int b = tid; b < NBLK; b += 256) {
        int beg = locT[(size_t)cb * NBLK + b];
        beg_s[b] = beg;
        len_s[b] = locT[(size_t)(cb + 1) * NBLK + b] - beg;
    }
    if (tid < 64) h[tid] = 0;
    __syncthreads();

    // pass 1: fine histogram (each thread walks its own micro-ranges)
    for (int b = tid; b < NBLK; b += 256) {
        int g0 = b * CHUNK + beg_s[b];
        int L = len_s[b];
        for (int j = 0; j < L; ++j) atomicAdd(&h[grel[g0 + j]], 1);
    }
    __syncthreads();

    // 64-wide scan -> rowptr, dis, cursors
    const int node0 = cb * 64;
    const int base = cbase[cb];
    int myv = (tid < 64) ? h[tid] : 0;
    ps[tid] = (tid < 64) ? myv : 0;
    __syncthreads();
    for (int off = 1; off < 64; off <<= 1) {
        int v = (tid >= off && tid < 64) ? ps[tid - off] : 0;
        __syncthreads();
        if (tid < 64) ps[tid] += v;
        __syncthreads();
    }
    if (tid < 64) {
        int excl = ps[tid] - myv;
        int n = node0 + tid;
        cur[tid] = base + excl;
        if (n < NN) {
            rowptr[n] = base + excl;
            dis[n] = rsqrtf((float)myv + 1.0f);  // +1 = self-loop
        }
    }
    __syncthreads();

    // pass 2: place entries (private region [base, base+T))
    for (int b = tid; b < NBLK; b += 256) {
        int g0 = b * CHUNK + beg_s[b];
        int L = len_s[b];
        for (int j = 0; j < L; ++j) {
            int g = g0 + j;
            int pos = atomicAdd(&cur[grel[g]], 1);  // LDS atomic only
            entries[pos] = gsrc[g];
        }
    }
}

// ---- xws = dis[n] * (x @ W1) -> bf16 [NN,32]; x is [NN,128] bf16 or fp32 ----
__global__ __launch_bounds__(256) void k_xw1(const void* __restrict__ xv, const void* __restrict__ W1v,
                                             const float* __restrict__ dis,
                                             const int* __restrict__ flag, u16* __restrict__ xwb) {
    __shared__ float wsm[FIN * HH];   // 16 KB
    __shared__ float xs[128][33];     // 16.9 KB
    const int f = *flag;
    const int tid = threadIdx.x;
    if (f) {
        const u16* W1 = (const u16*)W1v;
        for (int i = tid; i < FIN * HH; i += 256) wsm[i] = bf2f(W1[i]);
    } else {
        const float* W1 = (const float*)W1v;
        for (int i = tid; i < FIN * HH; i += 256) wsm[i] = W1[i];
    }
    const int n0 = blockIdx.x * 128;
    const int ct = tid & 7, rg = tid >> 3;
    const int lr = tid >> 1, lh = tid & 1;
    int ln = n0 + lr; if (ln >= NN) ln = NN - 1;
    float acc[4][4] = {};
    for (int kc = 0; kc < FIN; kc += 32) {
        __syncthreads();
        float* dq = &xs[lr][lh * 16];
        if (f) {
            const u16* lp = (const u16*)xv + (size_t)ln * FIN + lh * 16 + kc;
            uint4 a = *(const uint4*)lp;
            uint4 b = *(const uint4*)(lp + 8);
            u32 aw[4] = {a.x, a.y, a.z, a.w}, bw[4] = {b.x, b.y, b.z, b.w};
            #pragma unroll
            for (int i = 0; i < 4; ++i) {
                dq[2*i]     = bf2f((u16)(aw[i] & 0xffffu));
                dq[2*i+1]   = bf2f((u16)(aw[i] >> 16));
                dq[8+2*i]   = bf2f((u16)(bw[i] & 0xffffu));
                dq[8+2*i+1] = bf2f((u16)(bw[i] >> 16));
            }
        } else {
            const float* lp = (const float*)xv + (size_t)ln * FIN + lh * 16 + kc;
            #pragma unroll
            for (int i = 0; i < 4; ++i) {
                float4 t = *(const float4*)(lp + 4 * i);
                dq[4*i] = t.x; dq[4*i+1] = t.y; dq[4*i+2] = t.z; dq[4*i+3] = t.w;
            }
        }
        __syncthreads();
        #pragma unroll
        for (int k = 0; k < 32; ++k) {
            float4 wv = *(const float4*)&wsm[(kc + k) * HH + ct * 4];
            #pragma unroll
            for (int j = 0; j < 4; ++j) {
                float xvv = xs[rg * 4 + j][k];
                acc[j][0] = fmaf(xvv, wv.x, acc[j][0]);
                acc[j][1] = fmaf(xvv, wv.y, acc[j][1]);
                acc[j][2] = fmaf(xvv, wv.z, acc[j][2]);
                acc[j][3] = fmaf(xvv, wv.w, acc[j][3]);
            }
        }
    }
    #pragma unroll
    for (int j = 0; j < 4; ++j) {
        int n = n0 + rg * 4 + j;
        if (n < NN) {
            float dd = dis[n];
            ushort4 o;
            o.x = f2bf(dd * acc[j][0]); o.y = f2bf(dd * acc[j][1]);
            o.z = f2bf(dd * acc[j][2]); o.w = f2bf(dd * acc[j][3]);
            *(ushort4*)&xwb[(size_t)n * HH + ct * 4] = o;
        }
    }
}

// ---- xws = dis[n] * (h1 @ W2) -> bf16; h1 is bf16 [NN,32] (internal) ----
__global__ __launch_bounds__(256) void k_xw2(const u16* __restrict__ h1, const void* __restrict__ W2v,
                                             const float* __restrict__ dis,
                                             const int* __restrict__ flag, u16* __restrict__ xwb) {
    __shared__ float wsm[HH * HH];
    __shared__ float xs[128][33];
    const int f = *flag;
    const int tid = threadIdx.x;
    if (f) {
        const u16* W2 = (const u16*)W2v;
        for (int i = tid; i < HH * HH; i += 256) wsm[i] = bf2f(W2[i]);
    } else {
        const float* W2 = (const float*)W2v;
        for (int i = tid; i < HH * HH; i += 256) wsm[i] = W2[i];
    }
    const int n0 = blockIdx.x * 128;
    const int lr = tid >> 1, lh = tid & 1;
    int ln = n0 + lr; if (ln >= NN) ln = NN - 1;
    const u16* lp = h1 + (size_t)ln * HH + lh * 16;
    uint4 a = *(const uint4*)lp;
    uint4 b = *(const uint4*)(lp + 8);
    float* dq = &xs[lr][lh * 16];
    u32 aw[4] = {a.x, a.y, a.z, a.w}, bw[4] = {b.x, b.y, b.z, b.w};
    #pragma unroll
    for (int i = 0; i < 4; ++i) {
        dq[2*i]     = bf2f((u16)(aw[i] & 0xffffu));
        dq[2*i+1]   = bf2f((u16)(aw[i] >> 16));
        dq[8+2*i]   = bf2f((u16)(bw[i] & 0xffffu));
        dq[8+2*i+1] = bf2f((u16)(bw[i] >> 16));
    }
    __syncthreads();
    const int ct = tid & 7, rg = tid >> 3;
    float acc[4][4] = {};
    #pragma unroll
    for (int k = 0; k < 32; ++k) {
        float4 wv = *(const float4*)&wsm[k * HH + ct * 4];
        #pragma unroll
        for (int j = 0; j < 4; ++j) {
            float xv = xs[rg * 4 + j][k];
            acc[j][0] = fmaf(xv, wv.x, acc[j][0]);
            acc[j][1] = fmaf(xv, wv.y, acc[j][1]);
            acc[j][2] = fmaf(xv, wv.z, acc[j][2]);
            acc[j][3] = fmaf(xv, wv.w, acc[j][3]);
        }
    }
    #pragma unroll
    for (int j = 0; j < 4; ++j) {
        int n = n0 + rg * 4 + j;
        if (n < NN) {
            float dd = dis[n];
            ushort4 o;
            o.x = f2bf(dd * acc[j][0]); o.y = f2bf(dd * acc[j][1]);
            o.z = f2bf(dd * acc[j][2]); o.w = f2bf(dd * acc[j][3]);
            *(ushort4*)&xwb[(size_t)n * HH + ct * 4] = o;
        }
    }
}

// ---- CSR gather + fused epilogue (+ optional fused classifier) ----
// 16 lanes per node, u32 loads (2 channels/lane): one wave instruction moves
// 4 rows x 64 B. out[n] = tanh( dis[n]*(xws[n] + sum xws[s]) + bias ).
// NN == 3125*16 exactly, so no bounds checks / early returns.
__global__ __launch_bounds__(256) void k_gather(const int* __restrict__ rowptr, const u16* __restrict__ entries,
                                                const u16* __restrict__ xws, const float* __restrict__ dis,
                                                const void* __restrict__ bv, const int* __restrict__ flag,
                                                int force16, u16* __restrict__ dst16, float* __restrict__ dst32,
                                                int do_cls, const void* __restrict__ Wcv,
                                                const void* __restrict__ bcv, void* __restrict__ outv) {
    __shared__ float hrow[16][32];
    __shared__ float wcs[HH * CC];
    __shared__ float bcs[CC];
    const int f = *flag;
    const int tid = threadIdx.x;
    if (do_cls) {
        if (f) {
            const u16* Wc = (const u16*)Wcv;
            for (int i = tid; i < HH * CC; i += 256) wcs[i] = bf2f(Wc[i]);
            if (tid < CC) bcs[tid] = bf2f(((const u16*)bcv)[tid]);
        } else {
            const float* Wc = (const float*)Wcv;
            for (int i = tid; i < HH * CC; i += 256) wcs[i] = Wc[i];
            if (tid < CC) bcs[tid] = ((const float*)bcv)[tid];
        }
    }
    const int nl = tid >> 4;                 // node-local 0..15
    const int g = blockIdx.x * 16 + nl;      // node (< NN always)
    const int c0 = (tid & 15) * 2;           // channel pair
    float b0, b1;
    if (f) { b0 = bf2f(((const u16*)bv)[c0]); b1 = bf2f(((const u16*)bv)[c0 + 1]); }
    else   { b0 = ((const float*)bv)[c0];     b1 = ((const float*)bv)[c0 + 1]; }
    const int beg = rowptr[g], end = rowptr[g + 1];
    const float dd = dis[g];
    u32 sw = *(const u32*)&xws[(size_t)g * HH + c0];   // self (pre-scaled)
    float aL0 = bf2f((u16)(sw & 0xffffu)), aH0 = bf2f((u16)(sw >> 16));
    float aL1 = 0.f, aH1 = 0.f, aL2 = 0.f, aH2 = 0.f, aL3 = 0.f, aH3 = 0.f;
    int i = beg;
    for (; i + 4 <= end; i += 4) {
        int s0 = entries[i], s1 = entries[i + 1], s2 = entries[i + 2], s3 = entries[i + 3];
        u32 w0 = *(const u32*)&xws[(size_t)s0 * HH + c0];
        u32 w1 = *(const u32*)&xws[(size_t)s1 * HH + c0];
        u32 w2 = *(const u32*)&xws[(size_t)s2 * HH + c0];
        u32 w3 = *(const u32*)&xws[(size_t)s3 * HH + c0];
        aL0 += bf2f((u16)(w0 & 0xffffu)); aH0 += bf2f((u16)(w0 >> 16));
        aL1 += bf2f((u16)(w1 & 0xffffu)); aH1 += bf2f((u16)(w1 >> 16));
        aL2 += bf2f((u16)(w2 & 0xffffu)); aH2 += bf2f((u16)(w2 >> 16));
        aL3 += bf2f((u16)(w3 & 0xffffu)); aH3 += bf2f((u16)(w3 >> 16));
    }
    for (; i < end; ++i) {
        int s = entries[i];
        u32 w = *(const u32*)&xws[(size_t)s * HH + c0];
        aL0 += bf2f((u16)(w & 0xffffu)); aH0 += bf2f((u16)(w >> 16));
    }
    float vLo = tanhf(fmaf(dd, (aL0 + aL1) + (aL2 + aL3), b0));
    float vHi = tanhf(fmaf(dd, (aH0 + aH1) + (aH2 + aH3), b1));
    size_t idx = (size_t)g * HH + c0;
    if (force16 | f) {
        u32 o = (u32)f2bf(vLo) | ((u32)f2bf(vHi) << 16);
        *(u32*)&dst16[idx] = o;
    } else {
        *(float2*)&dst32[idx] = make_float2(vLo, vHi);
    }
    if (do_cls) {
        hrow[nl][c0] = vLo; hrow[nl][c0 + 1] = vHi;
        __syncthreads();
        // 16 nodes x 16 classes == 256 threads, one logit each
        int cl = tid & 15;
        float acc = bcs[cl];
        #pragma unroll
        for (int k = 0; k < HH; ++k) acc = fmaf(hrow[nl][k], wcs[k * CC + cl], acc);
        size_t oi = (size_t)g * CC + cl;
        if (f) ((u16*)outv)[oi] = f2bf(acc);
        else   ((float*)outv)[oi] = acc;
    }
}

extern "C" void kernel_launch(void* const* d_in, const int* in_sizes, int n_in,
                              void* d_out, int out_size, void* d_ws, size_t ws_size,
                              hipStream_t stream) {
    const void* x  = d_in[0];
    const int*  ei = (const int*)d_in[1];
    const void* W1 = d_in[2];
    const void* b1 = d_in[3];
    const void* W2 = d_in[4];
    const void* b2 = d_in[5];
    const void* Wc = d_in[6];
    const void* bc = d_in[7];
    const int* srcv = ei;
    const int* dstv = ei + EE;

    // ws layout (bytes), total ~8.05 MB:
    //   [0, 4096)            flag
    //   [4096, 208896)       rowptr int[N+1]
    //   [208896, 413696)     dis f32[N]
    //   [413696, 417792)     cbase int[NB+1]
    //   [417792, 421888)     btot int[NB]
    //   [421888, 1646500)    locT int[(NB+1)*NBLK] (1.22 MB)
    //   [1646592, 4846592)   xwb  bf16[N*32]
    //   [4846592, 8046592)   entries u16[E]
    char*  ws     = (char*)d_ws;
    int*   flag   = (int*)ws;
    int*   rowptr = (int*)(ws + 4096);
    float* dis    = (float*)(ws + 208896);
    int*   cbase  = (int*)(ws + 413696);
    int*   btot   = (int*)(ws + 417792);
    int*   locT   = (int*)(ws + 421888);
    u16*   xwb    = (u16*)(ws + 1646592);
    u16*   entries= (u16*)(ws + 4846592);

    // Coarse-sorted chunks live in d_out's head (consumed by k_fine before h1
    // is written there). gsrc: EE*2 = 3.2 MB, grel: EE*1 = 1.6 MB -> 4.8 MB.
    u16*   gsrc = (u16*)d_out;
    u8*    grel = (u8*)d_out + (size_t)EE * 2;

    // h1 (bf16, internal) lives in d_out's head; h2 goes to its final slot.
    u16*   h1    = (u16*)d_out;
    u16*   h2_16 = (u16*)d_out + (size_t)NN * CC;
    float* h2_32 = (float*)d_out + (size_t)NN * CC;

    // deterministic CSR build: block-major LDS counting-sort (private
    // coalesced writes), then per-bucket fine regroup. Zero global atomics.
    k_place<<<NBLK, 256, 0, stream>>>(srcv, dstv, locT, gsrc, grel);
    k_btot<<<NB, 256, 0, stream>>>(locT, btot);
    k_cscan<<<1, 1024, 0, stream>>>(btot, cbase, rowptr, (const u32*)x, flag);
    k_fine<<<NB, 256, 0, stream>>>(locT, cbase, gsrc, grel, rowptr, dis, entries);

    // layer 1: xws1 (dis-scaled) -> gather (fused agg+bias+tanh) -> h1 (bf16)
    k_xw1<<<(NN + 127) / 128, 256, 0, stream>>>(x, W1, dis, flag, xwb);
    k_gather<<<NN / 16, 256, 0, stream>>>(rowptr, entries, xwb, dis, b1, flag,
                                          1, h1, (float*)nullptr,
                                          0, nullptr, nullptr, nullptr);

    // layer 2: xws2 (reads h1) -> gather+classifier -> h2 + logits
    k_xw2<<<(NN + 127) / 128, 256, 0, stream>>>(h1, W2, dis, flag, xwb);
    k_gather<<<NN / 16, 256, 0, stream>>>(rowptr, entries, xwb, dis, b2, flag,
                                          0, h2_16, h2_32,
                                          1, Wc, bc, d_out);
}

// Round 7
// 191.849 us; speedup vs baseline: 6.9102x; 1.0077x over previous
//
#include <hip/hip_runtime.h>
#include <hip/hip_bf16.h>

#define NN 50000
#define EE 1600000
#define FIN 128
#define HH 32
#define CC 16
#define NB 782        // ceil(NN/64) coarse dst-buckets of 64 nodes
#define NBLK 782      // edge-chunk blocks: 782 * 2048 >= EE
#define CHUNK 2048
#define FCAP 3072     // LDS staging capacity in k_fine (bucket avg ~2046)

typedef unsigned short u16;
typedef unsigned int u32;
typedef unsigned char u8;

__device__ __forceinline__ float bf2f(u16 u) {
    union { u32 i; float f; } v; v.i = ((u32)u) << 16; return v.f;
}
__device__ __forceinline__ u16 f2bf(float f) {
    union { float f; u32 i; } v; v.f = f;
    u32 x = v.i;
    return (u16)((x + 0x7fffu + ((x >> 16) & 1u)) >> 16);  // RNE
}

// ---- block-major coarse sort: each block LDS-sorts its 2048-edge chunk by
//      dst>>6 and streams (src16, rel8) to its PRIVATE contiguous region.
//      locT[cb][b] = local exclusive offset of bucket cb within chunk b. ----
__global__ __launch_bounds__(256) void k_place(const int* __restrict__ src, const int* __restrict__ dst,
                                               int* __restrict__ locT,
                                               u16* __restrict__ gsrc, u8* __restrict__ grel) {
    __shared__ int dst_s[CHUNK];      // 8 KB
    __shared__ u16 s_src[CHUNK];      // 4 KB
    __shared__ u8  s_rel[CHUNK];      // 2 KB
    __shared__ int cur[NB];           // 3.1 KB (histogram -> cursors)
    __shared__ int ps[256];           // 1 KB
    const int tid = threadIdx.x, blk = blockIdx.x;
    const int e0 = blk * CHUNK;
    int cnt = EE - e0; if (cnt > CHUNK) cnt = CHUNK;   // cnt % 16 == 0 always

    // stage dst chunk (coalesced uint4)
    const uint4* gd4 = (const uint4*)(dst + e0);
    for (int i = tid; i < cnt / 4; i += 256) ((uint4*)dst_s)[i] = gd4[i];
    for (int i = tid; i < NB; i += 256) cur[i] = 0;
    __syncthreads();

    // LDS histogram of dst>>6
    for (int k = 0; k < CHUNK / 256; ++k) {
        int i = k * 256 + tid;
        if (i < cnt) atomicAdd(&cur[dst_s[i] >> 6], 1);
    }
    __syncthreads();

    // exclusive scan over 782 bins (4 bins/thread + 256-wide scan)
    const int bi = tid * 4;
    int v0 = 0, v1 = 0, v2 = 0, v3 = 0;
    if (bi < NB)     v0 = cur[bi];
    if (bi + 1 < NB) v1 = cur[bi + 1];
    if (bi + 2 < NB) v2 = cur[bi + 2];
    if (bi + 3 < NB) v3 = cur[bi + 3];
    ps[tid] = v0 + v1 + v2 + v3;
    __syncthreads();
    for (int off = 1; off < 256; off <<= 1) {
        int t = (tid >= off) ? ps[tid - off] : 0;
        __syncthreads();
        ps[tid] += t;
        __syncthreads();
    }
    int run = (tid == 0) ? 0 : ps[tid - 1];
    if (bi < NB)     { cur[bi] = run;     locT[(size_t)bi * NBLK + blk] = run;       run += v0; }
    if (bi + 1 < NB) { cur[bi + 1] = run; locT[(size_t)(bi + 1) * NBLK + blk] = run; run += v1; }
    if (bi + 2 < NB) { cur[bi + 2] = run; locT[(size_t)(bi + 2) * NBLK + blk] = run; run += v2; }
    if (bi + 3 < NB) { cur[bi + 3] = run; locT[(size_t)(bi + 3) * NBLK + blk] = run; run += v3; }
    if (tid == 255) locT[(size_t)NB * NBLK + blk] = ps[255];  // chunk total
    __syncthreads();

    // counting-sort into LDS (src read coalesced from global)
    for (int k = 0; k < CHUNK / 256; ++k) {
        int i = k * 256 + tid;
        if (i < cnt) {
            int d = dst_s[i];
            int pos = atomicAdd(&cur[d >> 6], 1);  // LDS atomic only
            s_src[pos] = (u16)src[e0 + i];
            s_rel[pos] = (u8)(d & 63);
        }
    }
    __syncthreads();

    // stream out to private region (fully coalesced dwordx4)
    const uint4* ss = (const uint4*)s_src;
    uint4* gs = (uint4*)(gsrc + (size_t)blk * CHUNK);
    for (int i = tid; i < (cnt * 2) / 16; i += 256) gs[i] = ss[i];
    const uint4* sr = (const uint4*)s_rel;
    uint4* gr = (uint4*)(grel + (size_t)blk * CHUNK);
    for (int i = tid; i < cnt / 16; i += 256) gr[i] = sr[i];
}

// ---- bucket totals from locT rows (coalesced) ----
__global__ __launch_bounds__(256) void k_btot(const int* __restrict__ locT, int* __restrict__ btot) {
    __shared__ int ps[256];
    const int cb = blockIdx.x;
    int s = 0;
    for (int b = threadIdx.x; b < NBLK; b += 256)
        s += locT[(size_t)(cb + 1) * NBLK + b] - locT[(size_t)cb * NBLK + b];
    ps[threadIdx.x] = s;
    __syncthreads();
    for (int off = 128; off > 0; off >>= 1) {
        if (threadIdx.x < off) ps[threadIdx.x] += ps[threadIdx.x + off];
        __syncthreads();
    }
    if (threadIdx.x == 0) btot[cb] = ps[0];
}

// ---- single-block: dtype probe + scan over bucket totals (3 KB) ----
__global__ __launch_bounds__(1024) void k_cscan(const int* __restrict__ btot, int* __restrict__ cbase,
                                                int* __restrict__ rowptr,
                                                const u32* __restrict__ xw_words, int* __restrict__ flag) {
    __shared__ int ps[1024];
    __shared__ int cs;
    const int t = threadIdx.x;
    if (t == 0) cs = 0;
    __syncthreads();
    if (t < 512) {
        float v = fabsf(bf2f((u16)(xw_words[t] & 0xffffu)));
        if (v >= 6.0e-8f && v <= 64.0f) atomicAdd(&cs, 1);
    }
    int myv = (t < NB) ? btot[t] : 0;
    ps[t] = myv;
    __syncthreads();
    for (int off = 1; off < 1024; off <<= 1) {
        int v = (t >= off) ? ps[t - off] : 0;
        __syncthreads();
        ps[t] += v;
        __syncthreads();
    }
    if (t < NB) cbase[t] = ps[t] - myv;  // exclusive
    if (t == 0) {
        cbase[NB] = EE; rowptr[NN] = EE;
        *flag = (cs > 384) ? 1 : 0;      // bf16 data -> sane exponents ~100%
    }
}

// ---- fused fine stage (per bucket): stage bucket edges into LDS while
//      histogramming, 64-wide scan -> rowptr+dis, LDS counting-sort, then
//      COALESCED stream of entries. Fallback to global path if T > FCAP. ----
__global__ __launch_bounds__(256) void k_fine(const int* __restrict__ locT, const int* __restrict__ cbase,
                                              const u16* __restrict__ gsrc, const u8* __restrict__ grel,
                                              int* __restrict__ rowptr, float* __restrict__ dis,
                                              u16* __restrict__ entries) {
    __shared__ int beg_s[NBLK];       // 3.1 KB
    __shared__ int fo[NBLK + 1];      // 3.1 KB (lens -> exclusive offsets)
    __shared__ int ps[256];
    __shared__ int h[64];
    __shared__ int cur[64];
    __shared__ u16 lsrc[FCAP];        // 6 KB
    __shared__ u8  lrel[FCAP];        // 3 KB
    __shared__ u16 lout[FCAP];        // 6 KB
    const int tid = threadIdx.x, cb = blockIdx.x;

    for (int b = tid; b < NBLK; b += 256) {
        int beg = locT[(size_t)cb * NBLK + b];
        beg_s[b] = beg;
        fo[b] = locT[(size_t)(cb + 1) * NBLK + b] - beg;  // len (for now)
    }
    if (tid < 64) h[tid] = 0;
    __syncthreads();

    // exclusive scan of lens -> fo (4 elems/thread covers 782)
    const int b0 = tid * 4;
    int a0 = 0, a1 = 0, a2 = 0, a3 = 0;
    if (b0 < NBLK)     a0 = fo[b0];
    if (b0 + 1 < NBLK) a1 = fo[b0 + 1];
    if (b0 + 2 < NBLK) a2 = fo[b0 + 2];
    if (b0 + 3 < NBLK) a3 = fo[b0 + 3];
    ps[tid] = a0 + a1 + a2 + a3;
    __syncthreads();
    for (int off = 1; off < 256; off <<= 1) {
        int v = (tid >= off) ? ps[tid - off] : 0;
        __syncthreads();
        ps[tid] += v;
        __syncthreads();
    }
    int run = (tid == 0) ? 0 : ps[tid - 1];
    if (b0 < NBLK)     { fo[b0] = run;     run += a0; }
    if (b0 + 1 < NBLK) { fo[b0 + 1] = run; run += a1; }
    if (b0 + 2 < NBLK) { fo[b0 + 2] = run; run += a2; }
    if (b0 + 3 < NBLK) { fo[b0 + 3] = run; run += a3; }
    if (tid == 255) fo[NBLK] = ps[255];  // total T
    __syncthreads();
    const int T = fo[NBLK];
    const int base = cbase[cb];
    const bool staged = (T <= FCAP);

    // pass 1: stage to LDS (if it fits) + fine histogram
    if (staged) {
        for (int b = tid; b < NBLK; b += 256) {
            int g0 = b * CHUNK + beg_s[b];
            int o = fo[b];
            int L = fo[b + 1] - o;
            for (int j = 0; j < L; ++j) {
                u8 r = grel[g0 + j];
                lrel[o + j] = r;
                lsrc[o + j] = gsrc[g0 + j];
                atomicAdd(&h[r], 1);
            }
        }
    } else {
        for (int b = tid; b < NBLK; b += 256) {
            int g0 = b * CHUNK + beg_s[b];
            int L = fo[b + 1] - fo[b];
            for (int j = 0; j < L; ++j) atomicAdd(&h[grel[g0 + j]], 1);
        }
    }
    __syncthreads();

    // 64-wide scan -> rowptr, dis, cursors
    int myv = (tid < 64) ? h[tid] : 0;
    ps[tid] = (tid < 64) ? myv : 0;
    __syncthreads();
    for (int off = 1; off < 64; off <<= 1) {
        int v = (tid >= off && tid < 64) ? ps[tid - off] : 0;
        __syncthreads();
        if (tid < 64) ps[tid] += v;
        __syncthreads();
    }
    if (tid < 64) {
        int excl = ps[tid] - myv;
        int n = cb * 64 + tid;
        cur[tid] = staged ? excl : base + excl;
        if (n < NN) {
            rowptr[n] = base + excl;
            dis[n] = rsqrtf((float)myv + 1.0f);  // +1 = self-loop
        }
    }
    __syncthreads();

    // pass 2: counting-sort + output
    if (staged) {
        for (int i = tid; i < T; i += 256) {
            int pos = atomicAdd(&cur[lrel[i]], 1);  // LDS atomic only
            lout[pos] = lsrc[i];
        }
        __syncthreads();
        for (int i = tid; i < T; i += 256) entries[base + i] = lout[i];  // coalesced
    } else {
        for (int b = tid; b < NBLK; b += 256) {
            int g0 = b * CHUNK + beg_s[b];
            int L = fo[b + 1] - fo[b];
            for (int j = 0; j < L; ++j) {
                int g = g0 + j;
                int pos = atomicAdd(&cur[grel[g]], 1);
                entries[pos] = gsrc[g];
            }
        }
    }
}

// ---- xws = dis[n] * (x @ W1) -> bf16 [NN,32]; x is [NN,128] bf16 or fp32 ----
__global__ __launch_bounds__(256) void k_xw1(const void* __restrict__ xv, const void* __restrict__ W1v,
                                             const float* __restrict__ dis,
                                             const int* __restrict__ flag, u16* __restrict__ xwb) {
    __shared__ float wsm[FIN * HH];   // 16 KB
    __shared__ float xs[128][33];     // 16.9 KB
    const int f = *flag;
    const int tid = threadIdx.x;
    if (f) {
        const u16* W1 = (const u16*)W1v;
        for (int i = tid; i < FIN * HH; i += 256) wsm[i] = bf2f(W1[i]);
    } else {
        const float* W1 = (const float*)W1v;
        for (int i = tid; i < FIN * HH; i += 256) wsm[i] = W1[i];
    }
    const int n0 = blockIdx.x * 128;
    const int ct = tid & 7, rg = tid >> 3;
    const int lr = tid >> 1, lh = tid & 1;
    int ln = n0 + lr; if (ln >= NN) ln = NN - 1;
    float acc[4][4] = {};
    for (int kc = 0; kc < FIN; kc += 32) {
        __syncthreads();
        float* dq = &xs[lr][lh * 16];
        if (f) {
            const u16* lp = (const u16*)xv + (size_t)ln * FIN + lh * 16 + kc;
            uint4 a = *(const uint4*)lp;
            uint4 b = *(const uint4*)(lp + 8);
            u32 aw[4] = {a.x, a.y, a.z, a.w}, bw[4] = {b.x, b.y, b.z, b.w};
            #pragma unroll
            for (int i = 0; i < 4; ++i) {
                dq[2*i]     = bf2f((u16)(aw[i] & 0xffffu));
                dq[2*i+1]   = bf2f((u16)(aw[i] >> 16));
                dq[8+2*i]   = bf2f((u16)(bw[i] & 0xffffu));
                dq[8+2*i+1] = bf2f((u16)(bw[i] >> 16));
            }
        } else {
            const float* lp = (const float*)xv + (size_t)ln * FIN + lh * 16 + kc;
            #pragma unroll
            for (int i = 0; i < 4; ++i) {
                float4 t = *(const float4*)(lp + 4 * i);
                dq[4*i] = t.x; dq[4*i+1] = t.y; dq[4*i+2] = t.z; dq[4*i+3] = t.w;
            }
        }
        __syncthreads();
        #pragma unroll
        for (int k = 0; k < 32; ++k) {
            float4 wv = *(const float4*)&wsm[(kc + k) * HH + ct * 4];
            #pragma unroll
            for (int j = 0; j < 4; ++j) {
                float xvv = xs[rg * 4 + j][k];
                acc[j][0] = fmaf(xvv, wv.x, acc[j][0]);
                acc[j][1] = fmaf(xvv, wv.y, acc[j][1]);
                acc[j][2] = fmaf(xvv, wv.z, acc[j][2]);
                acc[j][3] = fmaf(xvv, wv.w, acc[j][3]);
            }
        }
    }
    #pragma unroll
    for (int j = 0; j < 4; ++j) {
        int n = n0 + rg * 4 + j;
        if (n < NN) {
            float dd = dis[n];
            ushort4 o;
            o.x = f2bf(dd * acc[j][0]); o.y = f2bf(dd * acc[j][1]);
            o.z = f2bf(dd * acc[j][2]); o.w = f2bf(dd * acc[j][3]);
            *(ushort4*)&xwb[(size_t)n * HH + ct * 4] = o;
        }
    }
}

// ---- xws = dis[n] * (h1 @ W2) -> bf16; h1 is bf16 [NN,32] (internal) ----
__global__ __launch_bounds__(256) void k_xw2(const u16* __restrict__ h1, const void* __restrict__ W2v,
                                             const float* __restrict__ dis,
                                             const int* __restrict__ flag, u16* __restrict__ xwb) {
    __shared__ float wsm[HH * HH];
    __shared__ float xs[128][33];
    const int f = *flag;
    const int tid = threadIdx.x;
    if (f) {
        const u16* W2 = (const u16*)W2v;
        for (int i = tid; i < HH * HH; i += 256) wsm[i] = bf2f(W2[i]);
    } else {
        const float* W2 = (const float*)W2v;
        for (int i = tid; i < HH * HH; i += 256) wsm[i] = W2[i];
    }
    const int n0 = blockIdx.x * 128;
    const int lr = tid >> 1, lh = tid & 1;
    int ln = n0 + lr; if (ln >= NN) ln = NN - 1;
    const u16* lp = h1 + (size_t)ln * HH + lh * 16;
    uint4 a = *(const uint4*)lp;
    uint4 b = *(const uint4*)(lp + 8);
    float* dq = &xs[lr][lh * 16];
    u32 aw[4] = {a.x, a.y, a.z, a.w}, bw[4] = {b.x, b.y, b.z, b.w};
    #pragma unroll
    for (int i = 0; i < 4; ++i) {
        dq[2*i]     = bf2f((u16)(aw[i] & 0xffffu));
        dq[2*i+1]   = bf2f((u16)(aw[i] >> 16));
        dq[8+2*i]   = bf2f((u16)(bw[i] & 0xffffu));
        dq[8+2*i+1] = bf2f((u16)(bw[i] >> 16));
    }
    __syncthreads();
    const int ct = tid & 7, rg = tid >> 3;
    float acc[4][4] = {};
    #pragma unroll
    for (int k = 0; k < 32; ++k) {
        float4 wv = *(const float4*)&wsm[k * HH + ct * 4];
        #pragma unroll
        for (int j = 0; j < 4; ++j) {
            float xv = xs[rg * 4 + j][k];
            acc[j][0] = fmaf(xv, wv.x, acc[j][0]);
            acc[j][1] = fmaf(xv, wv.y, acc[j][1]);
            acc[j][2] = fmaf(xv, wv.z, acc[j][2]);
            acc[j][3] = fmaf(xv, wv.w, acc[j][3]);
        }
    }
    #pragma unroll
    for (int j = 0; j < 4; ++j) {
        int n = n0 + rg * 4 + j;
        if (n < NN) {
            float dd = dis[n];
            ushort4 o;
            o.x = f2bf(dd * acc[j][0]); o.y = f2bf(dd * acc[j][1]);
            o.z = f2bf(dd * acc[j][2]); o.w = f2bf(dd * acc[j][3]);
            *(ushort4*)&xwb[(size_t)n * HH + ct * 4] = o;
        }
    }
}

// ---- CSR gather + fused epilogue (+ optional fused classifier) ----
// 16 lanes per node, u32 loads (2 channels/lane); entries fetched 4-at-a-time
// via aligned ushort4. out[n] = tanh( dis[n]*(xws[n] + sum xws[s]) + bias ).
// NN == 3125*16 exactly, so no bounds checks / early returns.
__global__ __launch_bounds__(256) void k_gather(const int* __restrict__ rowptr, const u16* __restrict__ entries,
                                                const u16* __restrict__ xws, const float* __restrict__ dis,
                                                const void* __restrict__ bv, const int* __restrict__ flag,
                                                int force16, u16* __restrict__ dst16, float* __restrict__ dst32,
                                                int do_cls, const void* __restrict__ Wcv,
                                                const void* __restrict__ bcv, void* __restrict__ outv) {
    __shared__ float hrow[16][32];
    __shared__ float wcs[HH * CC];
    __shared__ float bcs[CC];
    const int f = *flag;
    const int tid = threadIdx.x;
    if (do_cls) {
        if (f) {
            const u16* Wc = (const u16*)Wcv;
            for (int i = tid; i < HH * CC; i += 256) wcs[i] = bf2f(Wc[i]);
            if (tid < CC) bcs[tid] = bf2f(((const u16*)bcv)[tid]);
        } else {
            const float* Wc = (const float*)Wcv;
            for (int i = tid; i < HH * CC; i += 256) wcs[i] = Wc[i];
            if (tid < CC) bcs[tid] = ((const float*)bcv)[tid];
        }
    }
    const int nl = tid >> 4;                 // node-local 0..15
    const int g = blockIdx.x * 16 + nl;      // node (< NN always)
    const int c0 = (tid & 15) * 2;           // channel pair
    float b0, b1;
    if (f) { b0 = bf2f(((const u16*)bv)[c0]); b1 = bf2f(((const u16*)bv)[c0 + 1]); }
    else   { b0 = ((const float*)bv)[c0];     b1 = ((const float*)bv)[c0 + 1]; }
    const int beg = rowptr[g], end = rowptr[g + 1];
    const float dd = dis[g];
    u32 sw = *(const u32*)&xws[(size_t)g * HH + c0];   // self (pre-scaled)
    float aL0 = bf2f((u16)(sw & 0xffffu)), aH0 = bf2f((u16)(sw >> 16));
    float aL1 = 0.f, aH1 = 0.f, aL2 = 0.f, aH2 = 0.f, aL3 = 0.f, aH3 = 0.f;
    int i = beg;
    for (; i < end && (i & 3); ++i) {        // head-align to 8 B
        u32 w = *(const u32*)&xws[(size_t)entries[i] * HH + c0];
        aL0 += bf2f((u16)(w & 0xffffu)); aH0 += bf2f((u16)(w >> 16));
    }
    for (; i + 4 <= end; i += 4) {
        ushort4 e4 = *(const ushort4*)&entries[i];   // 4 edges, one 8 B load
        u32 w0 = *(const u32*)&xws[(size_t)e4.x * HH + c0];
        u32 w1 = *(const u32*)&xws[(size_t)e4.y * HH + c0];
        u32 w2 = *(const u32*)&xws[(size_t)e4.z * HH + c0];
        u32 w3 = *(const u32*)&xws[(size_t)e4.w * HH + c0];
        aL0 += bf2f((u16)(w0 & 0xffffu)); aH0 += bf2f((u16)(w0 >> 16));
        aL1 += bf2f((u16)(w1 & 0xffffu)); aH1 += bf2f((u16)(w1 >> 16));
        aL2 += bf2f((u16)(w2 & 0xffffu)); aH2 += bf2f((u16)(w2 >> 16));
        aL3 += bf2f((u16)(w3 & 0xffffu)); aH3 += bf2f((u16)(w3 >> 16));
    }
    for (; i < end; ++i) {
        u32 w = *(const u32*)&xws[(size_t)entries[i] * HH + c0];
        aL0 += bf2f((u16)(w & 0xffffu)); aH0 += bf2f((u16)(w >> 16));
    }
    float vLo = tanhf(fmaf(dd, (aL0 + aL1) + (aL2 + aL3), b0));
    float vHi = tanhf(fmaf(dd, (aH0 + aH1) + (aH2 + aH3), b1));
    size_t idx = (size_t)g * HH + c0;
    if (force16 | f) {
        u32 o = (u32)f2bf(vLo) | ((u32)f2bf(vHi) << 16);
        *(u32*)&dst16[idx] = o;
    } else {
        *(float2*)&dst32[idx] = make_float2(vLo, vHi);
    }
    if (do_cls) {
        hrow[nl][c0] = vLo; hrow[nl][c0 + 1] = vHi;
        __syncthreads();
        // 16 nodes x 16 classes == 256 threads, one logit each
        int cl = tid & 15;
        float acc = bcs[cl];
        #pragma unroll
        for (int k = 0; k < HH; ++k) acc = fmaf(hrow[nl][k], wcs[k * CC + cl], acc);
        size_t oi = (size_t)g * CC + cl;
        if (f) ((u16*)outv)[oi] = f2bf(acc);
        else   ((float*)outv)[oi] = acc;
    }
}

extern "C" void kernel_launch(void* const* d_in, const int* in_sizes, int n_in,
                              void* d_out, int out_size, void* d_ws, size_t ws_size,
                              hipStream_t stream) {
    const void* x  = d_in[0];
    const int*  ei = (const int*)d_in[1];
    const void* W1 = d_in[2];
    const void* b1 = d_in[3];
    const void* W2 = d_in[4];
    const void* b2 = d_in[5];
    const void* Wc = d_in[6];
    const void* bc = d_in[7];
    const int* srcv = ei;
    const int* dstv = ei + EE;

    // ws layout (bytes), total ~9.27 MB (ws is 256 MiB per the poison fill):
    //   [0, 4096)            flag
    //   [4096, 208896)       rowptr int[N+1]
    //   [208896, 413696)     dis f32[N]
    //   [413696, 417792)     cbase int[NB+1]
    //   [417792, 421888)     btot int[NB]
    //   [421888, 2871296)    locT int[(NB+1)*NBLK] (2.45 MB)
    //   [2871296, 6071296)   xwb  bf16[N*32]
    //   [6071296, 9271296)   entries u16[E] (16 B aligned)
    char*  ws     = (char*)d_ws;
    int*   flag   = (int*)ws;
    int*   rowptr = (int*)(ws + 4096);
    float* dis    = (float*)(ws + 208896);
    int*   cbase  = (int*)(ws + 413696);
    int*   btot   = (int*)(ws + 417792);
    int*   locT   = (int*)(ws + 421888);
    u16*   xwb    = (u16*)(ws + 2871296);
    u16*   entries= (u16*)(ws + 6071296);

    // Coarse-sorted chunks live in d_out's head (consumed by k_fine before h1
    // is written there). gsrc: EE*2 = 3.2 MB, grel: EE*1 = 1.6 MB -> 4.8 MB.
    u16*   gsrc = (u16*)d_out;
    u8*    grel = (u8*)d_out + (size_t)EE * 2;

    // h1 (bf16, internal) lives in d_out's head; h2 goes to its final slot.
    u16*   h1    = (u16*)d_out;
    u16*   h2_16 = (u16*)d_out + (size_t)NN * CC;
    float* h2_32 = (float*)d_out + (size_t)NN * CC;

    // deterministic CSR build: block-major LDS counting-sort (private
    // coalesced writes), then per-bucket LDS-staged fine regroup.
    k_place<<<NBLK, 256, 0, stream>>>(srcv, dstv, locT, gsrc, grel);
    k_btot<<<NB, 256, 0, stream>>>(locT, btot);
    k_cscan<<<1, 1024, 0, stream>>>(btot, cbase, rowptr, (const u32*)x, flag);
    k_fine<<<NB, 256, 0, stream>>>(locT, cbase, gsrc, grel, rowptr, dis, entries);

    // layer 1: xws1 (dis-scaled) -> gather (fused agg+bias+tanh) -> h1 (bf16)
    k_xw1<<<(NN + 127) / 128, 256, 0, stream>>>(x, W1, dis, flag, xwb);
    k_gather<<<NN / 16, 256, 0, stream>>>(rowptr, entries, xwb, dis, b1, flag,
                                          1, h1, (float*)nullptr,
                                          0, nullptr, nullptr, nullptr);

    // layer 2: xws2 (reads h1) -> gather+classifier -> h2 + logits
    k_xw2<<<(NN + 127) / 128, 256, 0, stream>>>(h1, W2, dis, flag, xwb);
    k_gather<<<NN / 16, 256, 0, stream>>>(rowptr, entries, xwb, dis, b2, flag,
                                          0, h2_16, h2_32,
                                          1, Wc, bc, d_out);
}

// Round 8
// 185.797 us; speedup vs baseline: 7.1353x; 1.0326x over previous
//
#include <hip/hip_runtime.h>
#include <hip/hip_bf16.h>

#define NN 50000
#define EE 1600000
#define FIN 128
#define HH 32
#define CC 16
#define NB 782        // ceil(NN/64) coarse dst-buckets of 64 nodes
#define NBLK 782      // edge-chunk blocks: 782 * 2048 >= EE
#define CHUNK 2048
#define FCAP 3072     // LDS staging capacity in k_fine (bucket avg ~2046)

typedef unsigned short u16;
typedef unsigned int u32;
typedef unsigned char u8;

__device__ __forceinline__ float bf2f(u16 u) {
    union { u32 i; float f; } v; v.i = ((u32)u) << 16; return v.f;
}
__device__ __forceinline__ u16 f2bf(float f) {
    union { float f; u32 i; } v; v.f = f;
    u32 x = v.i;
    return (u16)((x + 0x7fffu + ((x >> 16) & 1u)) >> 16);  // RNE
}

// ---- block-major coarse sort: each block LDS-sorts its 2048-edge chunk by
//      dst>>6 and streams (src16, rel8) to its PRIVATE contiguous region.
//      locT[cb][b] = local exclusive offset of bucket cb within chunk b. ----
__global__ __launch_bounds__(256) void k_place(const int* __restrict__ src, const int* __restrict__ dst,
                                               int* __restrict__ locT,
                                               u16* __restrict__ gsrc, u8* __restrict__ grel) {
    __shared__ int dst_s[CHUNK];      // 8 KB
    __shared__ u16 s_src[CHUNK];      // 4 KB
    __shared__ u8  s_rel[CHUNK];      // 2 KB
    __shared__ int cur[NB];           // 3.1 KB (histogram -> cursors)
    __shared__ int ps[256];           // 1 KB
    const int tid = threadIdx.x, blk = blockIdx.x;
    const int e0 = blk * CHUNK;
    int cnt = EE - e0; if (cnt > CHUNK) cnt = CHUNK;   // cnt % 16 == 0 always

    // stage dst chunk (coalesced uint4)
    const uint4* gd4 = (const uint4*)(dst + e0);
    for (int i = tid; i < cnt / 4; i += 256) ((uint4*)dst_s)[i] = gd4[i];
    for (int i = tid; i < NB; i += 256) cur[i] = 0;
    __syncthreads();

    // LDS histogram of dst>>6
    for (int k = 0; k < CHUNK / 256; ++k) {
        int i = k * 256 + tid;
        if (i < cnt) atomicAdd(&cur[dst_s[i] >> 6], 1);
    }
    __syncthreads();

    // exclusive scan over 782 bins (4 bins/thread + 256-wide scan)
    const int bi = tid * 4;
    int v0 = 0, v1 = 0, v2 = 0, v3 = 0;
    if (bi < NB)     v0 = cur[bi];
    if (bi + 1 < NB) v1 = cur[bi + 1];
    if (bi + 2 < NB) v2 = cur[bi + 2];
    if (bi + 3 < NB) v3 = cur[bi + 3];
    ps[tid] = v0 + v1 + v2 + v3;
    __syncthreads();
    for (int off = 1; off < 256; off <<= 1) {
        int t = (tid >= off) ? ps[tid - off] : 0;
        __syncthreads();
        ps[tid] += t;
        __syncthreads();
    }
    int run = (tid == 0) ? 0 : ps[tid - 1];
    if (bi < NB)     { cur[bi] = run;     locT[(size_t)bi * NBLK + blk] = run;       run += v0; }
    if (bi + 1 < NB) { cur[bi + 1] = run; locT[(size_t)(bi + 1) * NBLK + blk] = run; run += v1; }
    if (bi + 2 < NB) { cur[bi + 2] = run; locT[(size_t)(bi + 2) * NBLK + blk] = run; run += v2; }
    if (bi + 3 < NB) { cur[bi + 3] = run; locT[(size_t)(bi + 3) * NBLK + blk] = run; run += v3; }
    if (tid == 255) locT[(size_t)NB * NBLK + blk] = ps[255];  // chunk total
    __syncthreads();

    // counting-sort into LDS (src read coalesced from global)
    for (int k = 0; k < CHUNK / 256; ++k) {
        int i = k * 256 + tid;
        if (i < cnt) {
            int d = dst_s[i];
            int pos = atomicAdd(&cur[d >> 6], 1);  // LDS atomic only
            s_src[pos] = (u16)src[e0 + i];
            s_rel[pos] = (u8)(d & 63);
        }
    }
    __syncthreads();

    // stream out to private region (fully coalesced dwordx4)
    const uint4* ss = (const uint4*)s_src;
    uint4* gs = (uint4*)(gsrc + (size_t)blk * CHUNK);
    for (int i = tid; i < (cnt * 2) / 16; i += 256) gs[i] = ss[i];
    const uint4* sr = (const uint4*)s_rel;
    uint4* gr = (uint4*)(grel + (size_t)blk * CHUNK);
    for (int i = tid; i < cnt / 16; i += 256) gr[i] = sr[i];
}

// ---- bucket totals from locT rows (coalesced); block 0 also runs the
//      dtype probe (flag=1 if float tensors are bf16). ----
__global__ __launch_bounds__(256) void k_btot(const int* __restrict__ locT, int* __restrict__ btot,
                                              const u32* __restrict__ xw_words, int* __restrict__ flag) {
    __shared__ int ps[256];
    __shared__ int cs;
    const int tid = threadIdx.x, cb = blockIdx.x;
    if (cb == 0) {
        if (tid == 0) cs = 0;
        __syncthreads();
        int c = 0;
        for (int i = tid; i < 512; i += 256) {
            float v = fabsf(bf2f((u16)(xw_words[i] & 0xffffu)));
            if (v >= 6.0e-8f && v <= 64.0f) c++;
        }
        atomicAdd(&cs, c);
        __syncthreads();
        if (tid == 0) *flag = (cs > 384) ? 1 : 0;
    }
    int s = 0;
    for (int b = tid; b < NBLK; b += 256)
        s += locT[(size_t)(cb + 1) * NBLK + b] - locT[(size_t)cb * NBLK + b];
    ps[tid] = s;
    __syncthreads();
    for (int off = 128; off > 0; off >>= 1) {
        if (tid < off) ps[tid] += ps[tid + off];
        __syncthreads();
    }
    if (tid == 0) btot[cb] = ps[0];
}

// ---- fused fine stage (per bucket): compute own base from btot (no global
//      scan kernel), stage bucket edges into LDS while histogramming, 64-wide
//      scan -> rowptr+dis, LDS counting-sort, coalesced entries stream. ----
__global__ __launch_bounds__(256) void k_fine(const int* __restrict__ locT, const int* __restrict__ btot,
                                              const u16* __restrict__ gsrc, const u8* __restrict__ grel,
                                              int* __restrict__ rowptr, float* __restrict__ dis,
                                              u16* __restrict__ entries) {
    __shared__ int beg_s[NBLK];       // 3.1 KB
    __shared__ int fo[NBLK + 1];      // 3.1 KB (lens -> exclusive offsets)
    __shared__ int ps[256];
    __shared__ int h[64];
    __shared__ int cur[64];
    __shared__ int sbase;
    __shared__ u16 lsrc[FCAP];        // 6 KB
    __shared__ u8  lrel[FCAP];        // 3 KB
    __shared__ u16 lout[FCAP];        // 6 KB
    const int tid = threadIdx.x, cb = blockIdx.x;

    for (int b = tid; b < NBLK; b += 256) {
        int beg = locT[(size_t)cb * NBLK + b];
        beg_s[b] = beg;
        fo[b] = locT[(size_t)(cb + 1) * NBLK + b] - beg;  // len (for now)
    }
    if (tid < 64) h[tid] = 0;

    // base = sum(btot[0..cb)) -- 256-wide strided load + tree reduce
    int bs = 0;
    for (int j = tid; j < cb; j += 256) bs += btot[j];
    ps[tid] = bs;
    __syncthreads();
    for (int off = 128; off > 0; off >>= 1) {
        if (tid < off) ps[tid] += ps[tid + off];
        __syncthreads();
    }
    if (tid == 0) sbase = ps[0];
    __syncthreads();
    const int base = sbase;

    // exclusive scan of lens -> fo (4 elems/thread covers 782)
    const int b0 = tid * 4;
    int a0 = 0, a1 = 0, a2 = 0, a3 = 0;
    if (b0 < NBLK)     a0 = fo[b0];
    if (b0 + 1 < NBLK) a1 = fo[b0 + 1];
    if (b0 + 2 < NBLK) a2 = fo[b0 + 2];
    if (b0 + 3 < NBLK) a3 = fo[b0 + 3];
    ps[tid] = a0 + a1 + a2 + a3;
    __syncthreads();
    for (int off = 1; off < 256; off <<= 1) {
        int v = (tid >= off) ? ps[tid - off] : 0;
        __syncthreads();
        ps[tid] += v;
        __syncthreads();
    }
    int run = (tid == 0) ? 0 : ps[tid - 1];
    if (b0 < NBLK)     { fo[b0] = run;     run += a0; }
    if (b0 + 1 < NBLK) { fo[b0 + 1] = run; run += a1; }
    if (b0 + 2 < NBLK) { fo[b0 + 2] = run; run += a2; }
    if (b0 + 3 < NBLK) { fo[b0 + 3] = run; run += a3; }
    if (tid == 255) fo[NBLK] = ps[255];  // total T
    __syncthreads();
    const int T = fo[NBLK];
    const bool staged = (T <= FCAP);

    // pass 1: stage to LDS (if it fits) + fine histogram
    if (staged) {
        for (int b = tid; b < NBLK; b += 256) {
            int g0 = b * CHUNK + beg_s[b];
            int o = fo[b];
            int L = fo[b + 1] - o;
            for (int j = 0; j < L; ++j) {
                u8 r = grel[g0 + j];
                lrel[o + j] = r;
                lsrc[o + j] = gsrc[g0 + j];
                atomicAdd(&h[r], 1);
            }
        }
    } else {
        for (int b = tid; b < NBLK; b += 256) {
            int g0 = b * CHUNK + beg_s[b];
            int L = fo[b + 1] - fo[b];
            for (int j = 0; j < L; ++j) atomicAdd(&h[grel[g0 + j]], 1);
        }
    }
    __syncthreads();

    // 64-wide scan -> rowptr, dis, cursors
    int myv = (tid < 64) ? h[tid] : 0;
    ps[tid] = (tid < 64) ? myv : 0;
    __syncthreads();
    for (int off = 1; off < 64; off <<= 1) {
        int v = (tid >= off && tid < 64) ? ps[tid - off] : 0;
        __syncthreads();
        if (tid < 64) ps[tid] += v;
        __syncthreads();
    }
    if (tid < 64) {
        int excl = ps[tid] - myv;
        int n = cb * 64 + tid;
        cur[tid] = staged ? excl : base + excl;
        if (n < NN) {
            rowptr[n] = base + excl;
            dis[n] = rsqrtf((float)myv + 1.0f);  // +1 = self-loop
        }
    }
    if (cb == NB - 1 && tid == 0) rowptr[NN] = EE;
    __syncthreads();

    // pass 2: counting-sort + output
    if (staged) {
        for (int i = tid; i < T; i += 256) {
            int pos = atomicAdd(&cur[lrel[i]], 1);  // LDS atomic only
            lout[pos] = lsrc[i];
        }
        __syncthreads();
        for (int i = tid; i < T; i += 256) entries[base + i] = lout[i];  // coalesced
    } else {
        for (int b = tid; b < NBLK; b += 256) {
            int g0 = b * CHUNK + beg_s[b];
            int L = fo[b + 1] - fo[b];
            for (int j = 0; j < L; ++j) {
                int g = g0 + j;
                int pos = atomicAdd(&cur[grel[g]], 1);
                entries[pos] = gsrc[g];
            }
        }
    }
}

// ---- xws = dis[n] * (x @ W1) -> bf16 [NN,32]; x is [NN,128] bf16 or fp32 ----
__global__ __launch_bounds__(256) void k_xw1(const void* __restrict__ xv, const void* __restrict__ W1v,
                                             const float* __restrict__ dis,
                                             const int* __restrict__ flag, u16* __restrict__ xwb) {
    __shared__ float wsm[FIN * HH];   // 16 KB
    __shared__ float xs[128][33];     // 16.9 KB
    const int f = *flag;
    const int tid = threadIdx.x;
    if (f) {
        const u16* W1 = (const u16*)W1v;
        for (int i = tid; i < FIN * HH; i += 256) wsm[i] = bf2f(W1[i]);
    } else {
        const float* W1 = (const float*)W1v;
        for (int i = tid; i < FIN * HH; i += 256) wsm[i] = W1[i];
    }
    const int n0 = blockIdx.x * 128;
    const int ct = tid & 7, rg = tid >> 3;
    const int lr = tid >> 1, lh = tid & 1;
    int ln = n0 + lr; if (ln >= NN) ln = NN - 1;
    float acc[4][4] = {};
    for (int kc = 0; kc < FIN; kc += 32) {
        __syncthreads();
        float* dq = &xs[lr][lh * 16];
        if (f) {
            const u16* lp = (const u16*)xv + (size_t)ln * FIN + lh * 16 + kc;
            uint4 a = *(const uint4*)lp;
            uint4 b = *(const uint4*)(lp + 8);
            u32 aw[4] = {a.x, a.y, a.z, a.w}, bw[4] = {b.x, b.y, b.z, b.w};
            #pragma unroll
            for (int i = 0; i < 4; ++i) {
                dq[2*i]     = bf2f((u16)(aw[i] & 0xffffu));
                dq[2*i+1]   = bf2f((u16)(aw[i] >> 16));
                dq[8+2*i]   = bf2f((u16)(bw[i] & 0xffffu));
                dq[8+2*i+1] = bf2f((u16)(bw[i] >> 16));
            }
        } else {
            const float* lp = (const float*)xv + (size_t)ln * FIN + lh * 16 + kc;
            #pragma unroll
            for (int i = 0; i < 4; ++i) {
                float4 t = *(const float4*)(lp + 4 * i);
                dq[4*i] = t.x; dq[4*i+1] = t.y; dq[4*i+2] = t.z; dq[4*i+3] = t.w;
            }
        }
        __syncthreads();
        #pragma unroll
        for (int k = 0; k < 32; ++k) {
            float4 wv = *(const float4*)&wsm[(kc + k) * HH + ct * 4];
            #pragma unroll
            for (int j = 0; j < 4; ++j) {
                float xvv = xs[rg * 4 + j][k];
                acc[j][0] = fmaf(xvv, wv.x, acc[j][0]);
                acc[j][1] = fmaf(xvv, wv.y, acc[j][1]);
                acc[j][2] = fmaf(xvv, wv.z, acc[j][2]);
                acc[j][3] = fmaf(xvv, wv.w, acc[j][3]);
            }
        }
    }
    #pragma unroll
    for (int j = 0; j < 4; ++j) {
        int n = n0 + rg * 4 + j;
        if (n < NN) {
            float dd = dis[n];
            ushort4 o;
            o.x = f2bf(dd * acc[j][0]); o.y = f2bf(dd * acc[j][1]);
            o.z = f2bf(dd * acc[j][2]); o.w = f2bf(dd * acc[j][3]);
            *(ushort4*)&xwb[(size_t)n * HH + ct * 4] = o;
        }
    }
}

// ---- layer-1 gather + fused xw2: h1 = tanh(dd*(sum)+b1) stays in LDS;
//      xws2[n][c] = dis[n] * sum_k h1[n][k]*W2[k][c] -> bf16 xwb2.
//      16 lanes/node, u32 channel-pair loads; NN % 16 == 0. ----
__global__ __launch_bounds__(256) void k_g1(const int* __restrict__ rowptr, const u16* __restrict__ entries,
                                            const u16* __restrict__ xws, const float* __restrict__ dis,
                                            const void* __restrict__ bv, const int* __restrict__ flag,
                                            const void* __restrict__ W2v, u16* __restrict__ xwb2) {
    __shared__ float hrow[16][32];
    __shared__ float w2s[HH * HH];
    const int f = *flag;
    const int tid = threadIdx.x;
    if (f) {
        const u16* W2 = (const u16*)W2v;
        for (int i = tid; i < HH * HH; i += 256) w2s[i] = bf2f(W2[i]);
    } else {
        const float* W2 = (const float*)W2v;
        for (int i = tid; i < HH * HH; i += 256) w2s[i] = W2[i];
    }
    const int nl = tid >> 4;                 // node-local 0..15
    const int g = blockIdx.x * 16 + nl;      // node (< NN always)
    const int c0 = (tid & 15) * 2;           // channel pair
    float b0, b1;
    if (f) { b0 = bf2f(((const u16*)bv)[c0]); b1 = bf2f(((const u16*)bv)[c0 + 1]); }
    else   { b0 = ((const float*)bv)[c0];     b1 = ((const float*)bv)[c0 + 1]; }
    const int beg = rowptr[g], end = rowptr[g + 1];
    const float dd = dis[g];
    u32 sw = *(const u32*)&xws[(size_t)g * HH + c0];   // self (pre-scaled)
    float aL0 = bf2f((u16)(sw & 0xffffu)), aH0 = bf2f((u16)(sw >> 16));
    float aL1 = 0.f, aH1 = 0.f, aL2 = 0.f, aH2 = 0.f, aL3 = 0.f, aH3 = 0.f;
    int i = beg;
    for (; i < end && (i & 3); ++i) {        // head-align to 8 B
        u32 w = *(const u32*)&xws[(size_t)entries[i] * HH + c0];
        aL0 += bf2f((u16)(w & 0xffffu)); aH0 += bf2f((u16)(w >> 16));
    }
    for (; i + 4 <= end; i += 4) {
        ushort4 e4 = *(const ushort4*)&entries[i];   // 4 edges, one 8 B load
        u32 w0 = *(const u32*)&xws[(size_t)e4.x * HH + c0];
        u32 w1 = *(const u32*)&xws[(size_t)e4.y * HH + c0];
        u32 w2 = *(const u32*)&xws[(size_t)e4.z * HH + c0];
        u32 w3 = *(const u32*)&xws[(size_t)e4.w * HH + c0];
        aL0 += bf2f((u16)(w0 & 0xffffu)); aH0 += bf2f((u16)(w0 >> 16));
        aL1 += bf2f((u16)(w1 & 0xffffu)); aH1 += bf2f((u16)(w1 >> 16));
        aL2 += bf2f((u16)(w2 & 0xffffu)); aH2 += bf2f((u16)(w2 >> 16));
        aL3 += bf2f((u16)(w3 & 0xffffu)); aH3 += bf2f((u16)(w3 >> 16));
    }
    for (; i < end; ++i) {
        u32 w = *(const u32*)&xws[(size_t)entries[i] * HH + c0];
        aL0 += bf2f((u16)(w & 0xffffu)); aH0 += bf2f((u16)(w >> 16));
    }
    float vLo = tanhf(fmaf(dd, (aL0 + aL1) + (aL2 + aL3), b0));
    float vHi = tanhf(fmaf(dd, (aH0 + aH1) + (aH2 + aH3), b1));
    hrow[nl][c0] = vLo; hrow[nl][c0 + 1] = vHi;
    __syncthreads();
    // xws2 = dd * (h1row @ W2), straight to bf16 (h1 never hits global)
    float a0 = 0.f, a1 = 0.f;
    #pragma unroll
    for (int k = 0; k < HH; ++k) {
        float hv = hrow[nl][k];
        a0 = fmaf(hv, w2s[k * HH + c0], a0);
        a1 = fmaf(hv, w2s[k * HH + c0 + 1], a1);
    }
    u32 o = (u32)f2bf(dd * a0) | ((u32)f2bf(dd * a1) << 16);
    *(u32*)&xwb2[(size_t)g * HH + c0] = o;
}

// ---- layer-2 gather + fused classifier: h2 (dtype per flag) + logits ----
__global__ __launch_bounds__(256) void k_g2(const int* __restrict__ rowptr, const u16* __restrict__ entries,
                                            const u16* __restrict__ xws, const float* __restrict__ dis,
                                            const void* __restrict__ bv, const int* __restrict__ flag,
                                            const void* __restrict__ Wcv, const void* __restrict__ bcv,
                                            void* __restrict__ outbase) {
    __shared__ float hrow[16][32];
    __shared__ float wcs[HH * CC];
    __shared__ float bcs[CC];
    const int f = *flag;
    const int tid = threadIdx.x;
    if (f) {
        const u16* Wc = (const u16*)Wcv;
        for (int i = tid; i < HH * CC; i += 256) wcs[i] = bf2f(Wc[i]);
        if (tid < CC) bcs[tid] = bf2f(((const u16*)bcv)[tid]);
    } else {
        const float* Wc = (const float*)Wcv;
        for (int i = tid; i < HH * CC; i += 256) wcs[i] = Wc[i];
        if (tid < CC) bcs[tid] = ((const float*)bcv)[tid];
    }
    const int nl = tid >> 4;                 // node-local 0..15
    const int g = blockIdx.x * 16 + nl;      // node (< NN always)
    const int c0 = (tid & 15) * 2;           // channel pair
    float b0, b1;
    if (f) { b0 = bf2f(((const u16*)bv)[c0]); b1 = bf2f(((const u16*)bv)[c0 + 1]); }
    else   { b0 = ((const float*)bv)[c0];     b1 = ((const float*)bv)[c0 + 1]; }
    const int beg = rowptr[g], end = rowptr[g + 1];
    const float dd = dis[g];
    u32 sw = *(const u32*)&xws[(size_t)g * HH + c0];   // self (pre-scaled)
    float aL0 = bf2f((u16)(sw & 0xffffu)), aH0 = bf2f((u16)(sw >> 16));
    float aL1 = 0.f, aH1 = 0.f, aL2 = 0.f, aH2 = 0.f, aL3 = 0.f, aH3 = 0.f;
    int i = beg;
    for (; i < end && (i & 3); ++i) {        // head-align to 8 B
        u32 w = *(const u32*)&xws[(size_t)entries[i] * HH + c0];
        aL0 += bf2f((u16)(w & 0xffffu)); aH0 += bf2f((u16)(w >> 16));
    }
    for (; i + 4 <= end; i += 4) {
        ushort4 e4 = *(const ushort4*)&entries[i];   // 4 edges, one 8 B load
        u32 w0 = *(const u32*)&xws[(size_t)e4.x * HH + c0];
        u32 w1 = *(const u32*)&xws[(size_t)e4.y * HH + c0];
        u32 w2 = *(const u32*)&xws[(size_t)e4.z * HH + c0];
        u32 w3 = *(const u32*)&xws[(size_t)e4.w * HH + c0];
        aL0 += bf2f((u16)(w0 & 0xffffu)); aH0 += bf2f((u16)(w0 >> 16));
        aL1 += bf2f((u16)(w1 & 0xffffu)); aH1 += bf2f((u16)(w1 >> 16));
        aL2 += bf2f((u16)(w2 & 0xffffu)); aH2 += bf2f((u16)(w2 >> 16));
        aL3 += bf2f((u16)(w3 & 0xffffu)); aH3 += bf2f((u16)(w3 >> 16));
    }
    for (; i < end; ++i) {
        u32 w = *(const u32*)&xws[(size_t)entries[i] * HH + c0];
        aL0 += bf2f((u16)(w & 0xffffu)); aH0 += bf2f((u16)(w >> 16));
    }
    float vLo = tanhf(fmaf(dd, (aL0 + aL1) + (aL2 + aL3), b0));
    float vHi = tanhf(fmaf(dd, (aH0 + aH1) + (aH2 + aH3), b1));
    size_t idx = (size_t)g * HH + c0;
    if (f) {
        u16* h2_16 = (u16*)outbase + (size_t)NN * CC;
        u32 o = (u32)f2bf(vLo) | ((u32)f2bf(vHi) << 16);
        *(u32*)&h2_16[idx] = o;
    } else {
        float* h2_32 = (float*)outbase + (size_t)NN * CC;
        *(float2*)&h2_32[idx] = make_float2(vLo, vHi);
    }
    hrow[nl][c0] = vLo; hrow[nl][c0 + 1] = vHi;
    __syncthreads();
    // 16 nodes x 16 classes == 256 threads, one logit each
    int cl = tid & 15;
    float acc = bcs[cl];
    #pragma unroll
    for (int k = 0; k < HH; ++k) acc = fmaf(hrow[nl][k], wcs[k * CC + cl], acc);
    size_t oi = (size_t)g * CC + cl;
    if (f) ((u16*)outbase)[oi] = f2bf(acc);
    else   ((float*)outbase)[oi] = acc;
}

extern "C" void kernel_launch(void* const* d_in, const int* in_sizes, int n_in,
                              void* d_out, int out_size, void* d_ws, size_t ws_size,
                              hipStream_t stream) {
    const void* x  = d_in[0];
    const int*  ei = (const int*)d_in[1];
    const void* W1 = d_in[2];
    const void* b1 = d_in[3];
    const void* W2 = d_in[4];
    const void* b2 = d_in[5];
    const void* Wc = d_in[6];
    const void* bc = d_in[7];
    const int* srcv = ei;
    const int* dstv = ei + EE;

    // ws layout (bytes), total ~12.5 MB (ws is 256 MiB per the poison fill):
    //   [0, 4096)            flag
    //   [4096, 208896)       rowptr int[N+1]
    //   [208896, 413696)     dis f32[N]
    //   [417792, 421888)     btot int[NB]
    //   [421888, 2871296)    locT int[(NB+1)*NBLK] (2.45 MB)
    //   [2871296, 6071296)   xwb  bf16[N*32]  (layer-1 dis-scaled xW)
    //   [6071296, 9271296)   entries u16[E] (16 B aligned)
    //   [9271296, 12471296)  xwb2 bf16[N*32]  (layer-2, written by k_g1)
    char*  ws     = (char*)d_ws;
    int*   flag   = (int*)ws;
    int*   rowptr = (int*)(ws + 4096);
    float* dis    = (float*)(ws + 208896);
    int*   btot   = (int*)(ws + 417792);
    int*   locT   = (int*)(ws + 421888);
    u16*   xwb    = (u16*)(ws + 2871296);
    u16*   entries= (u16*)(ws + 6071296);
    u16*   xwb2   = (u16*)(ws + 9271296);

    // Coarse-sorted chunks live in d_out's head (consumed by k_fine before
    // k_g2 writes outputs there). gsrc: 3.2 MB, grel: 1.6 MB -> 4.8 MB.
    u16*   gsrc = (u16*)d_out;
    u8*    grel = (u8*)d_out + (size_t)EE * 2;

    // deterministic CSR build: block-major LDS counting-sort (private
    // coalesced writes), per-bucket fine regroup with inline base-sum.
    k_place<<<NBLK, 256, 0, stream>>>(srcv, dstv, locT, gsrc, grel);
    k_btot<<<NB, 256, 0, stream>>>(locT, btot, (const u32*)x, flag);
    k_fine<<<NB, 256, 0, stream>>>(locT, btot, gsrc, grel, rowptr, dis, entries);

    // layer 1 matmul: xws1 (dis-scaled) -> bf16
    k_xw1<<<(NN + 127) / 128, 256, 0, stream>>>(x, W1, dis, flag, xwb);
    // layer-1 gather (agg+bias+tanh) fused with layer-2 matmul -> xwb2
    k_g1<<<NN / 16, 256, 0, stream>>>(rowptr, entries, xwb, dis, b1, flag, W2, xwb2);
    // layer-2 gather (agg+bias+tanh) fused with classifier -> h2 + logits
    k_g2<<<NN / 16, 256, 0, stream>>>(rowptr, entries, xwb2, dis, b2, flag, Wc, bc, d_out);
}

// Round 9
// 184.707 us; speedup vs baseline: 7.1774x; 1.0059x over previous
//
#include <hip/hip_runtime.h>
#include <hip/hip_bf16.h>

#define NN 50000
#define EE 1600000
#define FIN 128
#define HH 32
#define CC 16
#define NB 782        // ceil(NN/64) coarse dst-buckets of 64 nodes
#define NBLK 782      // edge-chunk blocks: 782 * 2048 >= EE
#define CHUNK 2048
#define FCAP 3072     // LDS staging capacity in k_fine (bucket avg ~2046)

typedef unsigned short u16;
typedef unsigned int u32;
typedef unsigned char u8;

__device__ __forceinline__ float bf2f(u16 u) {
    union { u32 i; float f; } v; v.i = ((u32)u) << 16; return v.f;
}
__device__ __forceinline__ u16 f2bf(float f) {
    union { float f; u32 i; } v; v.f = f;
    u32 x = v.i;
    return (u16)((x + 0x7fffu + ((x >> 16) & 1u)) >> 16);  // RNE
}

// ---- block-major coarse sort: each block LDS-sorts its 2048-edge chunk by
//      dst>>6 and streams (src16, rel8) to its PRIVATE contiguous region.
//      locT[cb][b] = local exclusive offset of bucket cb within chunk b. ----
__global__ __launch_bounds__(256) void k_place(const int* __restrict__ src, const int* __restrict__ dst,
                                               int* __restrict__ locT,
                                               u16* __restrict__ gsrc, u8* __restrict__ grel) {
    __shared__ int dst_s[CHUNK];      // 8 KB
    __shared__ u16 s_src[CHUNK];      // 4 KB
    __shared__ u8  s_rel[CHUNK];      // 2 KB
    __shared__ int cur[NB];           // 3.1 KB (histogram -> cursors)
    __shared__ int ps[256];           // 1 KB
    const int tid = threadIdx.x, blk = blockIdx.x;
    const int e0 = blk * CHUNK;
    int cnt = EE - e0; if (cnt > CHUNK) cnt = CHUNK;   // cnt % 16 == 0 always

    // stage dst chunk (coalesced uint4)
    const uint4* gd4 = (const uint4*)(dst + e0);
    for (int i = tid; i < cnt / 4; i += 256) ((uint4*)dst_s)[i] = gd4[i];
    for (int i = tid; i < NB; i += 256) cur[i] = 0;
    __syncthreads();

    // LDS histogram of dst>>6
    for (int k = 0; k < CHUNK / 256; ++k) {
        int i = k * 256 + tid;
        if (i < cnt) atomicAdd(&cur[dst_s[i] >> 6], 1);
    }
    __syncthreads();

    // exclusive scan over 782 bins (4 bins/thread + 256-wide scan)
    const int bi = tid * 4;
    int v0 = 0, v1 = 0, v2 = 0, v3 = 0;
    if (bi < NB)     v0 = cur[bi];
    if (bi + 1 < NB) v1 = cur[bi + 1];
    if (bi + 2 < NB) v2 = cur[bi + 2];
    if (bi + 3 < NB) v3 = cur[bi + 3];
    ps[tid] = v0 + v1 + v2 + v3;
    __syncthreads();
    for (int off = 1; off < 256; off <<= 1) {
        int t = (tid >= off) ? ps[tid - off] : 0;
        __syncthreads();
        ps[tid] += t;
        __syncthreads();
    }
    int run = (tid == 0) ? 0 : ps[tid - 1];
    if (bi < NB)     { cur[bi] = run;     locT[(size_t)bi * NBLK + blk] = run;       run += v0; }
    if (bi + 1 < NB) { cur[bi + 1] = run; locT[(size_t)(bi + 1) * NBLK + blk] = run; run += v1; }
    if (bi + 2 < NB) { cur[bi + 2] = run; locT[(size_t)(bi + 2) * NBLK + blk] = run; run += v2; }
    if (bi + 3 < NB) { cur[bi + 3] = run; locT[(size_t)(bi + 3) * NBLK + blk] = run; run += v3; }
    if (tid == 255) locT[(size_t)NB * NBLK + blk] = ps[255];  // chunk total
    __syncthreads();

    // counting-sort into LDS (src read coalesced from global)
    for (int k = 0; k < CHUNK / 256; ++k) {
        int i = k * 256 + tid;
        if (i < cnt) {
            int d = dst_s[i];
            int pos = atomicAdd(&cur[d >> 6], 1);  // LDS atomic only
            s_src[pos] = (u16)src[e0 + i];
            s_rel[pos] = (u8)(d & 63);
        }
    }
    __syncthreads();

    // stream out to private region (fully coalesced dwordx4)
    const uint4* ss = (const uint4*)s_src;
    uint4* gs = (uint4*)(gsrc + (size_t)blk * CHUNK);
    for (int i = tid; i < (cnt * 2) / 16; i += 256) gs[i] = ss[i];
    const uint4* sr = (const uint4*)s_rel;
    uint4* gr = (uint4*)(grel + (size_t)blk * CHUNK);
    for (int i = tid; i < cnt / 16; i += 256) gr[i] = sr[i];
}

// ---- bucket totals from locT rows (coalesced); block 0 also runs the
//      dtype probe (flag=1 if float tensors are bf16). ----
__global__ __launch_bounds__(256) void k_btot(const int* __restrict__ locT, int* __restrict__ btot,
                                              const u32* __restrict__ xw_words, int* __restrict__ flag) {
    __shared__ int ps[256];
    __shared__ int cs;
    const int tid = threadIdx.x, cb = blockIdx.x;
    if (cb == 0) {
        if (tid == 0) cs = 0;
        __syncthreads();
        int c = 0;
        for (int i = tid; i < 512; i += 256) {
            float v = fabsf(bf2f((u16)(xw_words[i] & 0xffffu)));
            if (v >= 6.0e-8f && v <= 64.0f) c++;
        }
        atomicAdd(&cs, c);
        __syncthreads();
        if (tid == 0) *flag = (cs > 384) ? 1 : 0;
    }
    int s = 0;
    for (int b = tid; b < NBLK; b += 256)
        s += locT[(size_t)(cb + 1) * NBLK + b] - locT[(size_t)cb * NBLK + b];
    ps[tid] = s;
    __syncthreads();
    for (int off = 128; off > 0; off >>= 1) {
        if (tid < off) ps[tid] += ps[tid + off];
        __syncthreads();
    }
    if (tid == 0) btot[cb] = ps[0];
}

// ---- fused fine stage (per bucket): compute own base from btot, stage
//      bucket edges into LDS while histogramming, 64-wide scan -> rowptr+dis,
//      LDS counting-sort, coalesced (u32-paired) entries stream. ----
__global__ __launch_bounds__(256) void k_fine(const int* __restrict__ locT, const int* __restrict__ btot,
                                              const u16* __restrict__ gsrc, const u8* __restrict__ grel,
                                              int* __restrict__ rowptr, float* __restrict__ dis,
                                              u16* __restrict__ entries) {
    __shared__ int beg_s[NBLK];       // 3.1 KB
    __shared__ int fo[NBLK + 1];      // 3.1 KB (lens -> exclusive offsets)
    __shared__ int ps[256];
    __shared__ int h[64];
    __shared__ int cur[64];
    __shared__ int sbase;
    __shared__ u16 lsrc[FCAP];        // 6 KB
    __shared__ u8  lrel[FCAP];        // 3 KB
    __shared__ u16 lout[FCAP];        // 6 KB
    const int tid = threadIdx.x, cb = blockIdx.x;

    for (int b = tid; b < NBLK; b += 256) {
        int beg = locT[(size_t)cb * NBLK + b];
        beg_s[b] = beg;
        fo[b] = locT[(size_t)(cb + 1) * NBLK + b] - beg;  // len (for now)
    }
    if (tid < 64) h[tid] = 0;

    // base = sum(btot[0..cb)) -- 256-wide strided load + tree reduce
    int bs = 0;
    for (int j = tid; j < cb; j += 256) bs += btot[j];
    ps[tid] = bs;
    __syncthreads();
    for (int off = 128; off > 0; off >>= 1) {
        if (tid < off) ps[tid] += ps[tid + off];
        __syncthreads();
    }
    if (tid == 0) sbase = ps[0];
    __syncthreads();
    const int base = sbase;

    // exclusive scan of lens -> fo (4 elems/thread covers 782)
    const int b0 = tid * 4;
    int a0 = 0, a1 = 0, a2 = 0, a3 = 0;
    if (b0 < NBLK)     a0 = fo[b0];
    if (b0 + 1 < NBLK) a1 = fo[b0 + 1];
    if (b0 + 2 < NBLK) a2 = fo[b0 + 2];
    if (b0 + 3 < NBLK) a3 = fo[b0 + 3];
    ps[tid] = a0 + a1 + a2 + a3;
    __syncthreads();
    for (int off = 1; off < 256; off <<= 1) {
        int v = (tid >= off) ? ps[tid - off] : 0;
        __syncthreads();
        ps[tid] += v;
        __syncthreads();
    }
    int run = (tid == 0) ? 0 : ps[tid - 1];
    if (b0 < NBLK)     { fo[b0] = run;     run += a0; }
    if (b0 + 1 < NBLK) { fo[b0 + 1] = run; run += a1; }
    if (b0 + 2 < NBLK) { fo[b0 + 2] = run; run += a2; }
    if (b0 + 3 < NBLK) { fo[b0 + 3] = run; run += a3; }
    if (tid == 255) fo[NBLK] = ps[255];  // total T
    __syncthreads();
    const int T = fo[NBLK];
    const bool staged = (T <= FCAP);

    // pass 1: stage to LDS (if it fits) + fine histogram
    if (staged) {
        for (int b = tid; b < NBLK; b += 256) {
            int g0 = b * CHUNK + beg_s[b];
            int o = fo[b];
            int L = fo[b + 1] - o;
            for (int j = 0; j < L; ++j) {
                u8 r = grel[g0 + j];
                lrel[o + j] = r;
                lsrc[o + j] = gsrc[g0 + j];
                atomicAdd(&h[r], 1);
            }
        }
    } else {
        for (int b = tid; b < NBLK; b += 256) {
            int g0 = b * CHUNK + beg_s[b];
            int L = fo[b + 1] - fo[b];
            for (int j = 0; j < L; ++j) atomicAdd(&h[grel[g0 + j]], 1);
        }
    }
    __syncthreads();

    // 64-wide scan -> rowptr, dis, cursors
    int myv = (tid < 64) ? h[tid] : 0;
    ps[tid] = (tid < 64) ? myv : 0;
    __syncthreads();
    for (int off = 1; off < 64; off <<= 1) {
        int v = (tid >= off && tid < 64) ? ps[tid - off] : 0;
        __syncthreads();
        if (tid < 64) ps[tid] += v;
        __syncthreads();
    }
    if (tid < 64) {
        int excl = ps[tid] - myv;
        int n = cb * 64 + tid;
        cur[tid] = staged ? excl : base + excl;
        if (n < NN) {
            rowptr[n] = base + excl;
            dis[n] = rsqrtf((float)myv + 1.0f);  // +1 = self-loop
        }
    }
    if (cb == NB - 1 && tid == 0) rowptr[NN] = EE;
    __syncthreads();

    // pass 2: counting-sort + output
    if (staged) {
        for (int i = tid; i < T; i += 256) {
            int pos = atomicAdd(&cur[lrel[i]], 1);  // LDS atomic only
            lout[pos] = lsrc[i];
        }
        __syncthreads();
        // stream out with u32-paired stores (entries base parity handled)
        const int st = base & 1;
        if (st && tid == 0) entries[base] = lout[0];
        for (int p = tid; ; p += 256) {
            int i = st + 2 * p;
            if (i + 1 >= T) break;
            u32 w = (u32)lout[i] | ((u32)lout[i + 1] << 16);
            *(u32*)&entries[base + i] = w;
        }
        if (((T - st) & 1) && tid == 0 && T > st) entries[base + T - 1] = lout[T - 1];
    } else {
        for (int b = tid; b < NBLK; b += 256) {
            int g0 = b * CHUNK + beg_s[b];
            int L = fo[b + 1] - fo[b];
            for (int j = 0; j < L; ++j) {
                int g = g0 + j;
                int pos = atomicAdd(&cur[grel[g]], 1);
                entries[pos] = gsrc[g];
            }
        }
    }
}

// ---- xws = dis[n] * (x @ W1) -> bf16 [NN,32]; x is [NN,128] bf16 or fp32 ----
__global__ __launch_bounds__(256) void k_xw1(const void* __restrict__ xv, const void* __restrict__ W1v,
                                             const float* __restrict__ dis,
                                             const int* __restrict__ flag, u16* __restrict__ xwb) {
    __shared__ float wsm[FIN * HH];   // 16 KB
    __shared__ float xs[128][33];     // 16.9 KB
    const int f = *flag;
    const int tid = threadIdx.x;
    if (f) {
        const u16* W1 = (const u16*)W1v;
        for (int i = tid; i < FIN * HH; i += 256) wsm[i] = bf2f(W1[i]);
    } else {
        const float* W1 = (const float*)W1v;
        for (int i = tid; i < FIN * HH; i += 256) wsm[i] = W1[i];
    }
    const int n0 = blockIdx.x * 128;
    const int ct = tid & 7, rg = tid >> 3;
    const int lr = tid >> 1, lh = tid & 1;
    int ln = n0 + lr; if (ln >= NN) ln = NN - 1;
    float acc[4][4] = {};
    for (int kc = 0; kc < FIN; kc += 32) {
        __syncthreads();
        float* dq = &xs[lr][lh * 16];
        if (f) {
            const u16* lp = (const u16*)xv + (size_t)ln * FIN + lh * 16 + kc;
            uint4 a = *(const uint4*)lp;
            uint4 b = *(const uint4*)(lp + 8);
            u32 aw[4] = {a.x, a.y, a.z, a.w}, bw[4] = {b.x, b.y, b.z, b.w};
            #pragma unroll
            for (int i = 0; i < 4; ++i) {
                dq[2*i]     = bf2f((u16)(aw[i] & 0xffffu));
                dq[2*i+1]   = bf2f((u16)(aw[i] >> 16));
                dq[8+2*i]   = bf2f((u16)(bw[i] & 0xffffu));
                dq[8+2*i+1] = bf2f((u16)(bw[i] >> 16));
            }
        } else {
            const float* lp = (const float*)xv + (size_t)ln * FIN + lh * 16 + kc;
            #pragma unroll
            for (int i = 0; i < 4; ++i) {
                float4 t = *(const float4*)(lp + 4 * i);
                dq[4*i] = t.x; dq[4*i+1] = t.y; dq[4*i+2] = t.z; dq[4*i+3] = t.w;
            }
        }
        __syncthreads();
        #pragma unroll
        for (int k = 0; k < 32; ++k) {
            float4 wv = *(const float4*)&wsm[(kc + k) * HH + ct * 4];
            #pragma unroll
            for (int j = 0; j < 4; ++j) {
                float xvv = xs[rg * 4 + j][k];
                acc[j][0] = fmaf(xvv, wv.x, acc[j][0]);
                acc[j][1] = fmaf(xvv, wv.y, acc[j][1]);
                acc[j][2] = fmaf(xvv, wv.z, acc[j][2]);
                acc[j][3] = fmaf(xvv, wv.w, acc[j][3]);
            }
        }
    }
    #pragma unroll
    for (int j = 0; j < 4; ++j) {
        int n = n0 + rg * 4 + j;
        if (n < NN) {
            float dd = dis[n];
            ushort4 o;
            o.x = f2bf(dd * acc[j][0]); o.y = f2bf(dd * acc[j][1]);
            o.z = f2bf(dd * acc[j][2]); o.w = f2bf(dd * acc[j][3]);
            *(ushort4*)&xwb[(size_t)n * HH + ct * 4] = o;
        }
    }
}

// ---- layer-1 gather + fused xw2 (8 lanes/node, uint2 = 4 channels/lane) ----
// h1 = tanh(dd*sum + b1) stays in LDS; xws2 = dd * (h1 @ W2) -> bf16 xwb2.
__global__ __launch_bounds__(256) void k_g1(const int* __restrict__ rowptr, const u16* __restrict__ entries,
                                            const u16* __restrict__ xws, const float* __restrict__ dis,
                                            const void* __restrict__ bv, const int* __restrict__ flag,
                                            const void* __restrict__ W2v, u16* __restrict__ xwb2) {
    __shared__ float hrow[32][33];
    __shared__ float w2s[HH * HH];
    const int f = *flag;
    const int tid = threadIdx.x;
    if (f) {
        const u16* W2 = (const u16*)W2v;
        for (int i = tid; i < HH * HH; i += 256) w2s[i] = bf2f(W2[i]);
    } else {
        const float* W2 = (const float*)W2v;
        for (int i = tid; i < HH * HH; i += 256) w2s[i] = W2[i];
    }
    const int nl = tid >> 3;                 // node-local 0..31
    const int graw = blockIdx.x * 32 + nl;
    const bool valid = graw < NN;
    const int g = valid ? graw : NN - 1;
    const int c0 = (tid & 7) * 4;            // channel quad
    float bb0, bb1, bb2, bb3;
    if (f) {
        const u16* b = (const u16*)bv;
        bb0 = bf2f(b[c0]); bb1 = bf2f(b[c0+1]); bb2 = bf2f(b[c0+2]); bb3 = bf2f(b[c0+3]);
    } else {
        const float* b = (const float*)bv;
        bb0 = b[c0]; bb1 = b[c0+1]; bb2 = b[c0+2]; bb3 = b[c0+3];
    }
    const int beg = rowptr[g], end = rowptr[g + 1];
    const float dd = dis[g];
    uint2 sw = *(const uint2*)&xws[(size_t)g * HH + c0];   // self (pre-scaled)
    float a00 = bf2f((u16)(sw.x & 0xffffu)), a01 = bf2f((u16)(sw.x >> 16));
    float a02 = bf2f((u16)(sw.y & 0xffffu)), a03 = bf2f((u16)(sw.y >> 16));
    float a10=0,a11=0,a12=0,a13=0, a20=0,a21=0,a22=0,a23=0, a30=0,a31=0,a32=0,a33=0;
    int i = beg;
    for (; i < end && (i & 3); ++i) {        // head-align to 8 B
        uint2 w = *(const uint2*)&xws[(size_t)entries[i] * HH + c0];
        a00 += bf2f((u16)(w.x & 0xffffu)); a01 += bf2f((u16)(w.x >> 16));
        a02 += bf2f((u16)(w.y & 0xffffu)); a03 += bf2f((u16)(w.y >> 16));
    }
    for (; i + 4 <= end; i += 4) {
        ushort4 e4 = *(const ushort4*)&entries[i];   // 4 edges, one 8 B load
        uint2 w0 = *(const uint2*)&xws[(size_t)e4.x * HH + c0];
        uint2 w1 = *(const uint2*)&xws[(size_t)e4.y * HH + c0];
        uint2 w2 = *(const uint2*)&xws[(size_t)e4.z * HH + c0];
        uint2 w3 = *(const uint2*)&xws[(size_t)e4.w * HH + c0];
        a00 += bf2f((u16)(w0.x & 0xffffu)); a01 += bf2f((u16)(w0.x >> 16));
        a02 += bf2f((u16)(w0.y & 0xffffu)); a03 += bf2f((u16)(w0.y >> 16));
        a10 += bf2f((u16)(w1.x & 0xffffu)); a11 += bf2f((u16)(w1.x >> 16));
        a12 += bf2f((u16)(w1.y & 0xffffu)); a13 += bf2f((u16)(w1.y >> 16));
        a20 += bf2f((u16)(w2.x & 0xffffu)); a21 += bf2f((u16)(w2.x >> 16));
        a22 += bf2f((u16)(w2.y & 0xffffu)); a23 += bf2f((u16)(w2.y >> 16));
        a30 += bf2f((u16)(w3.x & 0xffffu)); a31 += bf2f((u16)(w3.x >> 16));
        a32 += bf2f((u16)(w3.y & 0xffffu)); a33 += bf2f((u16)(w3.y >> 16));
    }
    for (; i < end; ++i) {
        uint2 w = *(const uint2*)&xws[(size_t)entries[i] * HH + c0];
        a00 += bf2f((u16)(w.x & 0xffffu)); a01 += bf2f((u16)(w.x >> 16));
        a02 += bf2f((u16)(w.y & 0xffffu)); a03 += bf2f((u16)(w.y >> 16));
    }
    float v0 = tanhf(fmaf(dd, (a00 + a10) + (a20 + a30), bb0));
    float v1 = tanhf(fmaf(dd, (a01 + a11) + (a21 + a31), bb1));
    float v2 = tanhf(fmaf(dd, (a02 + a12) + (a22 + a32), bb2));
    float v3 = tanhf(fmaf(dd, (a03 + a13) + (a23 + a33), bb3));
    hrow[nl][c0] = v0; hrow[nl][c0+1] = v1; hrow[nl][c0+2] = v2; hrow[nl][c0+3] = v3;
    __syncthreads();
    // xws2 = dd * (h1row @ W2), straight to bf16 (h1 never hits global)
    float s0 = 0.f, s1 = 0.f, s2 = 0.f, s3 = 0.f;
    #pragma unroll
    for (int k = 0; k < HH; ++k) {
        float hv = hrow[nl][k];
        s0 = fmaf(hv, w2s[k * HH + c0], s0);
        s1 = fmaf(hv, w2s[k * HH + c0 + 1], s1);
        s2 = fmaf(hv, w2s[k * HH + c0 + 2], s2);
        s3 = fmaf(hv, w2s[k * HH + c0 + 3], s3);
    }
    if (valid) {
        uint2 o;
        o.x = (u32)f2bf(dd * s0) | ((u32)f2bf(dd * s1) << 16);
        o.y = (u32)f2bf(dd * s2) | ((u32)f2bf(dd * s3) << 16);
        *(uint2*)&xwb2[(size_t)g * HH + c0] = o;
    }
}

// ---- layer-2 gather + fused classifier (8 lanes/node, uint2 loads) ----
__global__ __launch_bounds__(256) void k_g2(const int* __restrict__ rowptr, const u16* __restrict__ entries,
                                            const u16* __restrict__ xws, const float* __restrict__ dis,
                                            const void* __restrict__ bv, const int* __restrict__ flag,
                                            const void* __restrict__ Wcv, const void* __restrict__ bcv,
                                            void* __restrict__ outbase) {
    __shared__ float hrow[32][33];
    __shared__ float wcs[HH * CC];
    __shared__ float bcs[CC];
    const int f = *flag;
    const int tid = threadIdx.x;
    if (f) {
        const u16* Wc = (const u16*)Wcv;
        for (int i = tid; i < HH * CC; i += 256) wcs[i] = bf2f(Wc[i]);
        if (tid < CC) bcs[tid] = bf2f(((const u16*)bcv)[tid]);
    } else {
        const float* Wc = (const float*)Wcv;
        for (int i = tid; i < HH * CC; i += 256) wcs[i] = Wc[i];
        if (tid < CC) bcs[tid] = ((const float*)bcv)[tid];
    }
    const int nl = tid >> 3;                 // node-local 0..31
    const int graw = blockIdx.x * 32 + nl;
    const bool valid = graw < NN;
    const int g = valid ? graw : NN - 1;
    const int c0 = (tid & 7) * 4;            // channel quad
    float bb0, bb1, bb2, bb3;
    if (f) {
        const u16* b = (const u16*)bv;
        bb0 = bf2f(b[c0]); bb1 = bf2f(b[c0+1]); bb2 = bf2f(b[c0+2]); bb3 = bf2f(b[c0+3]);
    } else {
        const float* b = (const float*)bv;
        bb0 = b[c0]; bb1 = b[c0+1]; bb2 = b[c0+2]; bb3 = b[c0+3];
    }
    const int beg = rowptr[g], end = rowptr[g + 1];
    const float dd = dis[g];
    uint2 sw = *(const uint2*)&xws[(size_t)g * HH + c0];   // self (pre-scaled)
    float a00 = bf2f((u16)(sw.x & 0xffffu)), a01 = bf2f((u16)(sw.x >> 16));
    float a02 = bf2f((u16)(sw.y & 0xffffu)), a03 = bf2f((u16)(sw.y >> 16));
    float a10=0,a11=0,a12=0,a13=0, a20=0,a21=0,a22=0,a23=0, a30=0,a31=0,a32=0,a33=0;
    int i = beg;
    for (; i < end && (i & 3); ++i) {        // head-align to 8 B
        uint2 w = *(const uint2*)&xws[(size_t)entries[i] * HH + c0];
        a00 += bf2f((u16)(w.x & 0xffffu)); a01 += bf2f((u16)(w.x >> 16));
        a02 += bf2f((u16)(w.y & 0xffffu)); a03 += bf2f((u16)(w.y >> 16));
    }
    for (; i + 4 <= end; i += 4) {
        ushort4 e4 = *(const ushort4*)&entries[i];   // 4 edges, one 8 B load
        uint2 w0 = *(const uint2*)&xws[(size_t)e4.x * HH + c0];
        uint2 w1 = *(const uint2*)&xws[(size_t)e4.y * HH + c0];
        uint2 w2 = *(const uint2*)&xws[(size_t)e4.z * HH + c0];
        uint2 w3 = *(const uint2*)&xws[(size_t)e4.w * HH + c0];
        a00 += bf2f((u16)(w0.x & 0xffffu)); a01 += bf2f((u16)(w0.x >> 16));
        a02 += bf2f((u16)(w0.y & 0xffffu)); a03 += bf2f((u16)(w0.y >> 16));
        a10 += bf2f((u16)(w1.x & 0xffffu)); a11 += bf2f((u16)(w1.x >> 16));
        a12 += bf2f((u16)(w1.y & 0xffffu)); a13 += bf2f((u16)(w1.y >> 16));
        a20 += bf2f((u16)(w2.x & 0xffffu)); a21 += bf2f((u16)(w2.x >> 16));
        a22 += bf2f((u16)(w2.y & 0xffffu)); a23 += bf2f((u16)(w2.y >> 16));
        a30 += bf2f((u16)(w3.x & 0xffffu)); a31 += bf2f((u16)(w3.x >> 16));
        a32 += bf2f((u16)(w3.y & 0xffffu)); a33 += bf2f((u16)(w3.y >> 16));
    }
    for (; i < end; ++i) {
        uint2 w = *(const uint2*)&xws[(size_t)entries[i] * HH + c0];
        a00 += bf2f((u16)(w.x & 0xffffu)); a01 += bf2f((u16)(w.x >> 16));
        a02 += bf2f((u16)(w.y & 0xffffu)); a03 += bf2f((u16)(w.y >> 16));
    }
    float v0 = tanhf(fmaf(dd, (a00 + a10) + (a20 + a30), bb0));
    float v1 = tanhf(fmaf(dd, (a01 + a11) + (a21 + a31), bb1));
    float v2 = tanhf(fmaf(dd, (a02 + a12) + (a22 + a32), bb2));
    float v3 = tanhf(fmaf(dd, (a03 + a13) + (a23 + a33), bb3));
    if (valid) {
        size_t idx = (size_t)g * HH + c0;
        if (f) {
            u16* h2_16 = (u16*)outbase + (size_t)NN * CC;
            uint2 o;
            o.x = (u32)f2bf(v0) | ((u32)f2bf(v1) << 16);
            o.y = (u32)f2bf(v2) | ((u32)f2bf(v3) << 16);
            *(uint2*)&h2_16[idx] = o;
        } else {
            float* h2_32 = (float*)outbase + (size_t)NN * CC;
            *(float4*)&h2_32[idx] = make_float4(v0, v1, v2, v3);
        }
    }
    hrow[nl][c0] = v0; hrow[nl][c0+1] = v1; hrow[nl][c0+2] = v2; hrow[nl][c0+3] = v3;
    __syncthreads();
    // 32 nodes x 16 classes == 512 logits; each thread does 2 (nodes nA, nA+16)
    const int nA = tid >> 4, cl = tid & 15;
    const int nB = nA + 16;
    float accA = bcs[cl], accB = bcs[cl];
    #pragma unroll
    for (int k = 0; k < HH; ++k) {
        float wv = wcs[k * CC + cl];
        accA = fmaf(hrow[nA][k], wv, accA);
        accB = fmaf(hrow[nB][k], wv, accB);
    }
    const int gA = blockIdx.x * 32 + nA, gB = blockIdx.x * 32 + nB;
    if (gA < NN) {
        size_t oi = (size_t)gA * CC + cl;
        if (f) ((u16*)outbase)[oi] = f2bf(accA);
        else   ((float*)outbase)[oi] = accA;
    }
    if (gB < NN) {
        size_t oi = (size_t)gB * CC + cl;
        if (f) ((u16*)outbase)[oi] = f2bf(accB);
        else   ((float*)outbase)[oi] = accB;
    }
}

extern "C" void kernel_launch(void* const* d_in, const int* in_sizes, int n_in,
                              void* d_out, int out_size, void* d_ws, size_t ws_size,
                              hipStream_t stream) {
    const void* x  = d_in[0];
    const int*  ei = (const int*)d_in[1];
    const void* W1 = d_in[2];
    const void* b1 = d_in[3];
    const void* W2 = d_in[4];
    const void* b2 = d_in[5];
    const void* Wc = d_in[6];
    const void* bc = d_in[7];
    const int* srcv = ei;
    const int* dstv = ei + EE;

    // ws layout (bytes), total ~12.5 MB (ws is 256 MiB per the poison fill):
    //   [0, 4096)            flag
    //   [4096, 208896)       rowptr int[N+1]
    //   [208896, 413696)     dis f32[N]
    //   [417792, 421888)     btot int[NB]
    //   [421888, 2871296)    locT int[(NB+1)*NBLK] (2.45 MB)
    //   [2871296, 6071296)   xwb  bf16[N*32]  (layer-1 dis-scaled xW)
    //   [6071296, 9271296)   entries u16[E] (16 B aligned)
    //   [9271296, 12471296)  xwb2 bf16[N*32]  (layer-2, written by k_g1)
    char*  ws     = (char*)d_ws;
    int*   flag   = (int*)ws;
    int*   rowptr = (int*)(ws + 4096);
    float* dis    = (float*)(ws + 208896);
    int*   btot   = (int*)(ws + 417792);
    int*   locT   = (int*)(ws + 421888);
    u16*   xwb    = (u16*)(ws + 2871296);
    u16*   entries= (u16*)(ws + 6071296);
    u16*   xwb2   = (u16*)(ws + 9271296);

    // Coarse-sorted chunks live in d_out's head (consumed by k_fine before
    // k_g2 writes outputs there). gsrc: 3.2 MB, grel: 1.6 MB -> 4.8 MB.
    u16*   gsrc = (u16*)d_out;
    u8*    grel = (u8*)d_out + (size_t)EE * 2;

    // deterministic CSR build: block-major LDS counting-sort (private
    // coalesced writes), per-bucket fine regroup with inline base-sum.
    k_place<<<NBLK, 256, 0, stream>>>(srcv, dstv, locT, gsrc, grel);
    k_btot<<<NB, 256, 0, stream>>>(locT, btot, (const u32*)x, flag);
    k_fine<<<NB, 256, 0, stream>>>(locT, btot, gsrc, grel, rowptr, dis, entries);

    // layer 1 matmul: xws1 (dis-scaled) -> bf16
    k_xw1<<<(NN + 127) / 128, 256, 0, stream>>>(x, W1, dis, flag, xwb);
    // layer-1 gather (agg+bias+tanh) fused with layer-2 matmul -> xwb2
    k_g1<<<(NN + 31) / 32, 256, 0, stream>>>(rowptr, entries, xwb, dis, b1, flag, W2, xwb2);
    // layer-2 gather (agg+bias+tanh) fused with classifier -> h2 + logits
    k_g2<<<(NN + 31) / 32, 256, 0, stream>>>(rowptr, entries, xwb2, dis, b2, flag, Wc, bc, d_out);
}